// Round 10
// baseline (753.500 us; speedup 1.0000x reference)
//
#include <hip/hip_runtime.h>
#include <hip/hip_bf16.h>
#include <math.h>

// B=8, N=1024, F=64, HEADS=8, u1=128, u2=64
#define NB 8
#define NN 1024
#define NH 8

typedef __attribute__((ext_vector_type(8))) short bf16x8;
typedef __attribute__((ext_vector_type(4))) float f32x4;
typedef unsigned int u32;
typedef unsigned short u16;

__device__ __forceinline__ u16 f2bf(float f) {
    union { float f; u32 u; } v; v.f = f;
    const u32 u = v.u;
    return (u16)((u + 0x7fffu + ((u >> 16) & 1u)) >> 16);
}

// packed f32x2 -> bf16x2 (RTNE), dst.lo = lo, dst.hi = hi
__device__ __forceinline__ u32 cvt_pk_bf16(float lo, float hi) {
    u32 r;
    asm("v_cvt_pk_bf16_f32 %0, %1, %2" : "=v"(r) : "v"(lo), "v"(hi));
    return r;
}

// ---------------------------------------------------------------------------
// Mask bit-pack: A [B,N,N] f32 (0/1) -> bits [B*N, 32] u32 (bit=1 => masked)
// ---------------------------------------------------------------------------
__global__ __launch_bounds__(256) void mask_bits(const float* __restrict__ A,
                                                 u32* __restrict__ bits) {
    const int row = blockIdx.x;            // 0..B*N-1
    const int tid = threadIdx.x;
    const int lane = tid & 63;
    const float* __restrict__ ar = A + (size_t)row * NN;
#pragma unroll
    for (int it = 0; it < 4; ++it) {
        const int i = it * 256 + tid;
        const unsigned long long bal = __ballot(ar[i] != 0.0f);
        const int w0 = (it * 256 + (tid & ~63)) >> 5;
        if (lane == 0)  bits[(size_t)row * 32 + w0]     = (u32)bal;
        if (lane == 32) bits[(size_t)row * 32 + w0 + 1] = (u32)(bal >> 32);
    }
}

// ---------------------------------------------------------------------------
// Fused QKV projection -> bf16 outputs.
// Qb: [B,H,N,D] bf16 (pre-scaled), Kb: [B,H,N,D] bf16.
// VT: [B,H,D,N''] bf16 where key k is stored at position (within its
// 32-group) n'' = 8*((k>>2)&3) + (k&3) + 4*((k>>4)&1).  Then a 16B read at
// position 8g delivers keys key'(g,j) = 4g + (j&3) + 16*(j>>2) in slot j --
// exactly P's natural post-QK^T key order for the 16x16x32 PV A-fragment.
// ---------------------------------------------------------------------------
template <int KIN, int HD, int D>
__global__ __launch_bounds__(256)
void proj_qkv_bf(const float* __restrict__ X,
                 const float* __restrict__ Wq,
                 const float* __restrict__ Wk,
                 const float* __restrict__ Wv,
                 u16* __restrict__ Qb,
                 u16* __restrict__ Kb,
                 u16* __restrict__ VT,
                 const float qscale) {
    constexpr int RB  = 16;
    constexpr int CPW = HD / 256;          // 4 (layer1) or 2 (layer2)
    const int r0  = blockIdx.x * RB;
    const int b   = r0 >> 10;
    const int n0  = r0 & 1023;             // multiple of 16
    const int tid = threadIdx.x;

    __shared__ float xs[RB][KIN];
    for (int i = tid; i < RB * KIN / 4; i += 256) {
        const int rr = i / (KIN / 4), ff = (i % (KIN / 4)) * 4;
        *(float4*)&xs[rr][ff] = *(const float4*)&X[(size_t)(r0 + rr) * KIN + ff];
    }
    __syncthreads();

    const int c0 = CPW * tid;
    const int h  = c0 / D;
    const int d0 = c0 % D;
    const int bh = b * NH + h;

    const float* Ws[3] = {Wq, Wk, Wv};
#pragma unroll 1
    for (int w = 0; w < 3; ++w) {
        const float* __restrict__ W = Ws[w];
        float acc[RB][CPW];
#pragma unroll
        for (int rr = 0; rr < RB; ++rr)
#pragma unroll
            for (int k = 0; k < CPW; ++k) acc[rr][k] = 0.f;

#pragma unroll 4
        for (int f = 0; f < KIN; ++f) {
            float wv[CPW];
            if constexpr (CPW == 4) {
                const float4 t = *(const float4*)&W[(size_t)f * HD + c0];
                wv[0] = t.x; wv[1] = t.y; wv[2] = t.z; wv[3] = t.w;
            } else {
                const float2 t = *(const float2*)&W[(size_t)f * HD + c0];
                wv[0] = t.x; wv[1] = t.y;
            }
#pragma unroll
            for (int rr = 0; rr < RB; ++rr) {
                const float xv = xs[rr][f];
#pragma unroll
                for (int k = 0; k < CPW; ++k) acc[rr][k] = fmaf(xv, wv[k], acc[rr][k]);
            }
        }

        if (w == 2) {
            // V store with the 32-group permutation.  This block's 16 rows
            // are keys n0..n0+15 of group (n0&~31); grp = (n0>>4)&1 selects
            // the +4 half.  Rows {4a..4a+3} -> u32 words {4a, 4a+1} + 2*grp.
            const int grp = (n0 >> 4) & 1;
#pragma unroll
            for (int k = 0; k < CPW; ++k) {
                u32* dst = (u32*)&VT[((size_t)bh * D + d0 + k) * NN + (n0 & ~31)]
                           + 2 * grp;
                uint2 w0, w1, w2, w3;
                w0.x = (u32)f2bf(acc[0][k])  | ((u32)f2bf(acc[1][k])  << 16);
                w0.y = (u32)f2bf(acc[2][k])  | ((u32)f2bf(acc[3][k])  << 16);
                w1.x = (u32)f2bf(acc[4][k])  | ((u32)f2bf(acc[5][k])  << 16);
                w1.y = (u32)f2bf(acc[6][k])  | ((u32)f2bf(acc[7][k])  << 16);
                w2.x = (u32)f2bf(acc[8][k])  | ((u32)f2bf(acc[9][k])  << 16);
                w2.y = (u32)f2bf(acc[10][k]) | ((u32)f2bf(acc[11][k]) << 16);
                w3.x = (u32)f2bf(acc[12][k]) | ((u32)f2bf(acc[13][k]) << 16);
                w3.y = (u32)f2bf(acc[14][k]) | ((u32)f2bf(acc[15][k]) << 16);
                *(uint2*)(dst + 0)  = w0;
                *(uint2*)(dst + 4)  = w1;
                *(uint2*)(dst + 8)  = w2;
                *(uint2*)(dst + 12) = w3;
            }
        } else {
            u16* __restrict__ O = (w == 0) ? Qb : Kb;
            const float sc = (w == 0) ? qscale : 1.0f;
#pragma unroll
            for (int rr = 0; rr < RB; ++rr) {
                u16* dst = &O[((size_t)bh * NN + (n0 + rr)) * D + d0];
                if constexpr (CPW == 4) {
                    uint2 v;
                    v.x = (u32)f2bf(acc[rr][0] * sc) | ((u32)f2bf(acc[rr][1] * sc) << 16);
                    v.y = (u32)f2bf(acc[rr][2] * sc) | ((u32)f2bf(acc[rr][3] * sc) << 16);
                    *(uint2*)dst = v;
                } else {
                    u32 v = (u32)f2bf(acc[rr][0] * sc) | ((u32)f2bf(acc[rr][1] * sc) << 16);
                    *(u32*)dst = v;
                }
            }
        }
    }
}

// ---------------------------------------------------------------------------
// MFMA flash attention v8: 16x16x32 MFMA, 16 q-rows per WAVE, zero spill
// (true demand ~110 VGPR), no cross-lane exchange (V pre-permuted), no max
// tracking (scores O(1); exp2 overflow needs |s|>127), no LDS, no barriers.
// 1024 blocks x 4 independent waves = 4096 waves -> 4 waves/SIMD.
// QK^T swapped: s[kb] = mfma16(A=K,B=Q): lane(g,q16) reg r =
//   S[key=16kb+4g+r][q=q16]  (v2-verified layout, R3/R4).
// PV: A-frag slot (g,j) needs P[q16][key'(g,j)=4g+(j&3)+16(j>>2)] -- exactly
// the keys this lane holds; B-frag slots match because VT is pre-permuted.
// ---------------------------------------------------------------------------
template <int D>
__global__ __launch_bounds__(256, 2)
void attn_v8(const u16* __restrict__ Qb,
             const u16* __restrict__ Kb,
             const u16* __restrict__ VT,
             const u32* __restrict__ bits,
             float* __restrict__ O) {
    constexpr int ND4 = D / 32;            // QK k-steps per kb (4 / 2)
    constexpr int NDT = D / 16;            // PV d-tiles (8 / 4)

    const int tid  = threadIdx.x;
    const int w    = tid >> 6;
    const int lane = tid & 63;
    const int g    = lane >> 4;            // 0..3
    const int q16  = lane & 15;

    // 1024 blocks -> 8 XCDs x 8 bh x 16 q-quads (bijective; bid%8 = XCD)
    const int xcd    = blockIdx.x & 7;
    const int within = blockIdx.x >> 3;    // 0..127
    const int bh     = xcd * 8 + (within >> 4);
    const int b      = bh >> 3, h = bh & 7;
    const int q0     = ((within & 15) * 4 + w) * 16;   // 16 q-rows per wave

    const u16* __restrict__ qbase = Qb + (size_t)bh * NN * D;
    const u16* __restrict__ kbase = Kb + (size_t)bh * NN * D;
    const u16* __restrict__ vbase = VT + (size_t)bh * D * NN;
    const u32* __restrict__ brow  = bits + ((size_t)b * NN + q0 + q16) * 32;

    // Q as B-fragment: col=q16=q, k = f*32 + g*8 + j
    bf16x8 qf[ND4];
#pragma unroll
    for (int f = 0; f < ND4; ++f)
        qf[f] = *(const bf16x8*)&qbase[(size_t)(q0 + q16) * D + f * 32 + g * 8];

    f32x4 acc[NDT];
#pragma unroll
    for (int dt = 0; dt < NDT; ++dt) acc[dt] = (f32x4)0.f;
    float l = 0.f;                         // per-lane partial for q=q16

#pragma unroll 1
    for (int c4 = 0; c4 < 8; ++c4) {
        const uint4 bw4 = *(const uint4*)&brow[c4 * 4];
#pragma unroll
        for (int cc = 0; cc < 4; ++cc) {
            const int ch = c4 * 4 + cc;
            const int k0 = ch * 32;
            const u32 bw = (cc == 0) ? bw4.x : (cc == 1) ? bw4.y
                         : (cc == 2) ? bw4.z : bw4.w;

            // K A-fragments (row=q16 -> key, k = f*32 + g*8 + j)
            bf16x8 kf[2][ND4];
#pragma unroll
            for (int kb = 0; kb < 2; ++kb)
#pragma unroll
                for (int f = 0; f < ND4; ++f)
                    kf[kb][f] = *(const bf16x8*)
                        &kbase[(size_t)(k0 + kb * 16 + q16) * D + f * 32 + g * 8];

            // QK^T: two independent chains
            f32x4 s0 = (f32x4)0.f, s1 = (f32x4)0.f;
#pragma unroll
            for (int f = 0; f < ND4; ++f) {
                s0 = __builtin_amdgcn_mfma_f32_16x16x32_bf16(kf[0][f], qf[f], s0, 0, 0, 0);
                s1 = __builtin_amdgcn_mfma_f32_16x16x32_bf16(kf[1][f], qf[f], s1, 0, 0, 0);
            }

            // V B-fragments from permuted VT (col=q16 -> d, slots match P)
            bf16x8 vf[NDT];
#pragma unroll
            for (int dt = 0; dt < NDT; ++dt)
                vf[dt] = *(const bf16x8*)
                    &vbase[(size_t)(dt * 16 + q16) * NN + k0 + 8 * g];

            // mask + exp2 + partial l; reg r of s[kb] is key 16kb+4g+r
            const u32 sh = bw >> (g * 4);
            float p0[4], p1[4];
#pragma unroll
            for (int r = 0; r < 4; ++r) {
                float a = s0[r] - (((sh >> r) & 1u)        ? 1.0e9f : 0.f);
                float c = s1[r] - (((sh >> (16 + r)) & 1u) ? 1.0e9f : 0.f);
                p0[r] = exp2f(a);
                p1[r] = exp2f(c);
            }
            l += ((p0[0] + p0[1]) + (p0[2] + p0[3]))
               + ((p1[0] + p1[1]) + (p1[2] + p1[3]));

            // P -> A-frag words: slots j=0..3 = keys 4g+r (p0), j=4..7 = +16 (p1)
            union { u32 u[4]; bf16x8 v; } pa;
            pa.u[0] = cvt_pk_bf16(p0[0], p0[1]);
            pa.u[1] = cvt_pk_bf16(p0[2], p0[3]);
            pa.u[2] = cvt_pk_bf16(p1[0], p1[1]);
            pa.u[3] = cvt_pk_bf16(p1[2], p1[3]);

            // PV: one K=32 A-frag covers the whole chunk
#pragma unroll
            for (int dt = 0; dt < NDT; ++dt)
                acc[dt] = __builtin_amdgcn_mfma_f32_16x16x32_bf16(pa.v, vf[dt], acc[dt], 0, 0, 0);
        }
    }

    // l: sum the 4 g-group partials for each q16 (lanes q16+16g)
    l += __shfl_xor(l, 16);
    l += __shfl_xor(l, 32);
    const float inv = 1.0f / l;            // valid on every lane for its q16

    // C layout: row=q=4g+r (regs), col=d=dt*16+q16
    float ivr[4];
#pragma unroll
    for (int r = 0; r < 4; ++r) ivr[r] = __shfl(inv, g * 4 + r);
#pragma unroll
    for (int dt = 0; dt < NDT; ++dt)
#pragma unroll
        for (int r = 0; r < 4; ++r) {
            const int q = q0 + g * 4 + r;
            O[(((size_t)b * NN + q) * NH + h) * D + dt * 16 + q16] = acc[dt][r] * ivr[r];
        }
}

// ---------------------------------------------------------------------------
// Output projection (fp32): thread owns 4 consecutive output cols (float4
// weight loads shared across row-groups), 1 row per thread from LDS.
// ---------------------------------------------------------------------------
template <int CIN, int COUT, int RB>
__global__ __launch_bounds__(256)
void wo_proj2(const float* __restrict__ Hin,
              const float* __restrict__ Wo,
              float* __restrict__ Hout) {
    constexpr int CG = COUT / 4;           // col groups (32 / 16)
    static_assert(256 / CG == RB, "one row per thread");
    const int r0  = blockIdx.x * RB;
    const int tid = threadIdx.x;
    const int cg  = tid % CG;
    const int rg  = tid / CG;

    __shared__ float xs[RB][CIN];
    for (int i = tid; i < RB * CIN / 4; i += 256) {
        const int rr = i / (CIN / 4), ff = (i % (CIN / 4)) * 4;
        *(float4*)&xs[rr][ff] = *(const float4*)&Hin[(size_t)(r0 + rr) * CIN + ff];
    }
    __syncthreads();

    const float* __restrict__ wp = Wo + 4 * cg;
    float a0 = 0.f, a1 = 0.f, a2 = 0.f, a3 = 0.f;
#pragma unroll 8
    for (int f = 0; f < CIN; ++f) {
        const float4 wv = *(const float4*)&wp[(size_t)f * COUT];
        const float xv = xs[rg][f];
        a0 = fmaf(xv, wv.x, a0);
        a1 = fmaf(xv, wv.y, a1);
        a2 = fmaf(xv, wv.z, a2);
        a3 = fmaf(xv, wv.w, a3);
    }
    float4 o; o.x = a0; o.y = a1; o.z = a2; o.w = a3;
    *(float4*)&Hout[(size_t)(r0 + rg) * COUT + 4 * cg] = o;
}

// ---------------------------------------------------------------------------
// Mean over N + 3-layer MLP. One block per batch element.
// ---------------------------------------------------------------------------
__global__ void pool_mlp(const float* __restrict__ H2,
                         const float* __restrict__ W1, const float* __restrict__ b1,
                         const float* __restrict__ W2, const float* __restrict__ b2,
                         const float* __restrict__ W3, const float* __restrict__ b3,
                         float* __restrict__ out) {
    const int b = blockIdx.x;
    const int tid = threadIdx.x;       // 256
    __shared__ float red[4][64];
    __shared__ float mean[64];
    __shared__ float h1[32];
    __shared__ float h2[16];

    const int o = tid & 63;
    const int g = tid >> 6;
    float acc = 0.f;
    for (int n = g; n < NN; n += 4) acc += H2[((size_t)b * NN + n) * 64 + o];
    red[g][o] = acc;
    __syncthreads();
    if (g == 0) mean[o] = (red[0][o] + red[1][o] + red[2][o] + red[3][o]) * (1.0f / 1024.0f);
    __syncthreads();

    if (tid < 32) {
        float a = b1[tid];
#pragma unroll
        for (int f = 0; f < 64; ++f) a = fmaf(mean[f], W1[f * 32 + tid], a);
        h1[tid] = fmaxf(a, 0.f);
    }
    __syncthreads();
    if (tid < 16) {
        float a = b2[tid];
#pragma unroll
        for (int f = 0; f < 32; ++f) a = fmaf(h1[f], W2[f * 16 + tid], a);
        h2[tid] = fmaxf(a, 0.f);
    }
    __syncthreads();
    if (tid == 0) {
        float a = b3[0];
#pragma unroll
        for (int f = 0; f < 16; ++f) a = fmaf(h2[f], W3[f], a);
        out[b] = a;
    }
}

// ---------------------------------------------------------------------------
extern "C" void kernel_launch(void* const* d_in, const int* in_sizes, int n_in,
                              void* d_out, int out_size, void* d_ws, size_t ws_size,
                              hipStream_t stream) {
    const float* X   = (const float*)d_in[0];
    const float* A   = (const float*)d_in[1];
    const float* Wq1 = (const float*)d_in[2];
    const float* Wk1 = (const float*)d_in[3];
    const float* Wv1 = (const float*)d_in[4];
    const float* Wo1 = (const float*)d_in[5];
    const float* Wq2 = (const float*)d_in[6];
    const float* Wk2 = (const float*)d_in[7];
    const float* Wv2 = (const float*)d_in[8];
    const float* Wo2 = (const float*)d_in[9];
    const float* W1  = (const float*)d_in[10];
    const float* b1  = (const float*)d_in[11];
    const float* W2  = (const float*)d_in[12];
    const float* b2  = (const float*)d_in[13];
    const float* W3  = (const float*)d_in[14];
    const float* b3  = (const float*)d_in[15];
    float* out = (float*)d_out;

    // workspace layout
    u32* bits = (u32*)d_ws;                       // 262144 u32 = 1MB
    u16* Qb1  = (u16*)(bits + 262144);            // 8M bf16 = 16MB
    u16* Kb1  = Qb1 + 8388608;
    u16* VT1  = Kb1 + 8388608;
    float* ctx1 = (float*)(VT1 + 8388608);        // 8M f32 [B,N,1024]
    float* H1   = ctx1 + 8388608;                 // 1M f32 [B,N,128]
    u16* Qb2  = (u16*)(H1 + 1048576);             // 4M bf16
    u16* Kb2  = Qb2 + 4194304;
    u16* VT2  = Kb2 + 4194304;
    float* ctx2 = (float*)(VT2 + 4194304);        // 4M f32 [B,N,512]
    float* H2   = ctx2 + 4194304;                 // 0.5M f32 [B,N,64]

    const int ROWS = NB * NN;                     // 8192
    const float LOG2E = 1.4426950408889634f;

    mask_bits<<<ROWS, 256, 0, stream>>>(A, bits);

    // ----- layer 1 (D = 128) -----
    proj_qkv_bf<64, 1024, 128><<<ROWS / 16, 256, 0, stream>>>(
        X, Wq1, Wk1, Wv1, Qb1, Kb1, VT1, 0.08838834764831845f * LOG2E);
    attn_v8<128><<<1024, 256, 0, stream>>>(Qb1, Kb1, VT1, bits, ctx1);
    wo_proj2<1024, 128, 8><<<ROWS / 8, 256, 0, stream>>>(ctx1, Wo1, H1);

    // ----- layer 2 (D = 64) -----
    proj_qkv_bf<128, 512, 64><<<ROWS / 16, 256, 0, stream>>>(
        H1, Wq2, Wk2, Wv2, Qb2, Kb2, VT2, 0.125f * LOG2E);
    attn_v8<64><<<1024, 256, 0, stream>>>(Qb2, Kb2, VT2, bits, ctx2);
    wo_proj2<512, 64, 16><<<ROWS / 16, 256, 0, stream>>>(ctx2, Wo2, H2);

    // ----- pool + MLP -----
    pool_mlp<<<NB, 256, 0, stream>>>(H2, W1, b1, W2, b2, W3, b3, out);
}

// Round 11
// 448.176 us; speedup vs baseline: 1.6813x; 1.6813x over previous
//
#include <hip/hip_runtime.h>
#include <hip/hip_bf16.h>
#include <math.h>

// B=8, N=1024, F=64, HEADS=8, u1=128, u2=64
#define NB 8
#define NN 1024
#define NH 8

typedef __attribute__((ext_vector_type(8))) short bf16x8;
typedef __attribute__((ext_vector_type(4))) float f32x4;
typedef unsigned int u32;
typedef unsigned short u16;

__device__ __forceinline__ u16 f2bf(float f) {
    union { float f; u32 u; } v; v.f = f;
    const u32 u = v.u;
    return (u16)((u + 0x7fffu + ((u >> 16) & 1u)) >> 16);
}

// packed f32x2 -> bf16x2 (RTNE), dst.lo = lo, dst.hi = hi
__device__ __forceinline__ u32 cvt_pk_bf16(float lo, float hi) {
    u32 r;
    asm("v_cvt_pk_bf16_f32 %0, %1, %2" : "=v"(r) : "v"(lo), "v"(hi));
    return r;
}

// ---------------------------------------------------------------------------
// Mask bit-pack: A [B,N,N] f32 (0/1) -> bits [B*N, 32] u32 (bit=1 => masked)
// ---------------------------------------------------------------------------
__global__ __launch_bounds__(256) void mask_bits(const float* __restrict__ A,
                                                 u32* __restrict__ bits) {
    const int row = blockIdx.x;            // 0..B*N-1
    const int tid = threadIdx.x;
    const int lane = tid & 63;
    const float* __restrict__ ar = A + (size_t)row * NN;
#pragma unroll
    for (int it = 0; it < 4; ++it) {
        const int i = it * 256 + tid;
        const unsigned long long bal = __ballot(ar[i] != 0.0f);
        const int w0 = (it * 256 + (tid & ~63)) >> 5;
        if (lane == 0)  bits[(size_t)row * 32 + w0]     = (u32)bal;
        if (lane == 32) bits[(size_t)row * 32 + w0 + 1] = (u32)(bal >> 32);
    }
}

// ---------------------------------------------------------------------------
// Fused QKV projection -> bf16 outputs.
// Qb: [B,H,N,D] bf16 (pre-scaled), Kb: [B,H,N,D] bf16.
// VT: CHUNK-MAJOR [bh][ch=32][D][32keys''] bf16 where within each 32-key
// group key k sits at n'' = 8*((k>>2)&3) + (k&3) + 4*((k>>4)&1) -- so a 16B
// read at position 8g delivers keys 4g+(j&3)+16*(j>>2) in slot j, exactly
// P's natural post-QK^T key order for the 16x16x32 PV A-fragment (R9-verified).
// ---------------------------------------------------------------------------
template <int KIN, int HD, int D>
__global__ __launch_bounds__(256)
void proj_qkv_bf(const float* __restrict__ X,
                 const float* __restrict__ Wq,
                 const float* __restrict__ Wk,
                 const float* __restrict__ Wv,
                 u16* __restrict__ Qb,
                 u16* __restrict__ Kb,
                 u16* __restrict__ VT,
                 const float qscale) {
    constexpr int RB  = 16;
    constexpr int CPW = HD / 256;          // 4 (layer1) or 2 (layer2)
    const int r0  = blockIdx.x * RB;
    const int b   = r0 >> 10;
    const int n0  = r0 & 1023;             // multiple of 16
    const int tid = threadIdx.x;

    __shared__ float xs[RB][KIN];
    for (int i = tid; i < RB * KIN / 4; i += 256) {
        const int rr = i / (KIN / 4), ff = (i % (KIN / 4)) * 4;
        *(float4*)&xs[rr][ff] = *(const float4*)&X[(size_t)(r0 + rr) * KIN + ff];
    }
    __syncthreads();

    const int c0 = CPW * tid;
    const int h  = c0 / D;
    const int d0 = c0 % D;
    const int bh = b * NH + h;

    const float* Ws[3] = {Wq, Wk, Wv};
#pragma unroll 1
    for (int w = 0; w < 3; ++w) {
        const float* __restrict__ W = Ws[w];
        float acc[RB][CPW];
#pragma unroll
        for (int rr = 0; rr < RB; ++rr)
#pragma unroll
            for (int k = 0; k < CPW; ++k) acc[rr][k] = 0.f;

#pragma unroll 4
        for (int f = 0; f < KIN; ++f) {
            float wv[CPW];
            if constexpr (CPW == 4) {
                const float4 t = *(const float4*)&W[(size_t)f * HD + c0];
                wv[0] = t.x; wv[1] = t.y; wv[2] = t.z; wv[3] = t.w;
            } else {
                const float2 t = *(const float2*)&W[(size_t)f * HD + c0];
                wv[0] = t.x; wv[1] = t.y;
            }
#pragma unroll
            for (int rr = 0; rr < RB; ++rr) {
                const float xv = xs[rr][f];
#pragma unroll
                for (int k = 0; k < CPW; ++k) acc[rr][k] = fmaf(xv, wv[k], acc[rr][k]);
            }
        }

        if (w == 2) {
            // V store, chunk-major + 32-group permutation.  This block's 16
            // rows are half of chunk ch = n0>>5; grp = (n0>>4)&1.
            const int ch  = n0 >> 5;
            const int grp = (n0 >> 4) & 1;
#pragma unroll
            for (int k = 0; k < CPW; ++k) {
                u32* dst = (u32*)&VT[(((size_t)bh * 32 + ch) * D + d0 + k) * 32]
                           + 2 * grp;
                uint2 w0, w1, w2, w3;
                w0.x = (u32)f2bf(acc[0][k])  | ((u32)f2bf(acc[1][k])  << 16);
                w0.y = (u32)f2bf(acc[2][k])  | ((u32)f2bf(acc[3][k])  << 16);
                w1.x = (u32)f2bf(acc[4][k])  | ((u32)f2bf(acc[5][k])  << 16);
                w1.y = (u32)f2bf(acc[6][k])  | ((u32)f2bf(acc[7][k])  << 16);
                w2.x = (u32)f2bf(acc[8][k])  | ((u32)f2bf(acc[9][k])  << 16);
                w2.y = (u32)f2bf(acc[10][k]) | ((u32)f2bf(acc[11][k]) << 16);
                w3.x = (u32)f2bf(acc[12][k]) | ((u32)f2bf(acc[13][k]) << 16);
                w3.y = (u32)f2bf(acc[14][k]) | ((u32)f2bf(acc[15][k]) << 16);
                *(uint2*)(dst + 0)  = w0;
                *(uint2*)(dst + 4)  = w1;
                *(uint2*)(dst + 8)  = w2;
                *(uint2*)(dst + 12) = w3;
            }
        } else {
            u16* __restrict__ O = (w == 0) ? Qb : Kb;
            const float sc = (w == 0) ? qscale : 1.0f;
#pragma unroll
            for (int rr = 0; rr < RB; ++rr) {
                u16* dst = &O[((size_t)bh * NN + (n0 + rr)) * D + d0];
                if constexpr (CPW == 4) {
                    uint2 v;
                    v.x = (u32)f2bf(acc[rr][0] * sc) | ((u32)f2bf(acc[rr][1] * sc) << 16);
                    v.y = (u32)f2bf(acc[rr][2] * sc) | ((u32)f2bf(acc[rr][3] * sc) << 16);
                    *(uint2*)dst = v;
                } else {
                    u32 v = (u32)f2bf(acc[rr][0] * sc) | ((u32)f2bf(acc[rr][1] * sc) << 16);
                    *(u32*)dst = v;
                }
            }
        }
    }
}

// ---------------------------------------------------------------------------
// MFMA flash attention v9: LDS-staged K/V shared by 4 waves (64 q-rows),
// 2-phase schedule with async-stage split (issue global loads -> compute
// chunk k from LDS -> barrier -> ds_write k+1 -> barrier).  Body math =
// v8 (verified): 16x16x32, swapped QK^T, V pre-permuted so PV needs no
// cross-lane exchange, no max tracking, per-lane l.
// K LDS is XOR-swizzled (content granule c -> slot c^(row&7)) so the
// 16-rows-per-lane fragment ds_reads are bank-conflict-free (G4).
// V LDS rows padded to 80B -> conflict-free frag reads.
// Grid 1024 blocks = 4 blocks/CU -> 16 waves/CU.
// ---------------------------------------------------------------------------
template <int D>
__global__ __launch_bounds__(256, 2)
void attn_v9(const u16* __restrict__ Qb,
             const u16* __restrict__ Kb,
             const u16* __restrict__ VT,
             const u32* __restrict__ bits,
             float* __restrict__ O) {
    constexpr int ND4 = D / 32;            // QK k-steps per kb (4 / 2)
    constexpr int NDT = D / 16;            // PV d-tiles (8 / 4)
    constexpr int KROWB = 2 * D;           // K LDS row bytes (256 / 128)
    constexpr int KUPR  = D / 16;          // K 32B-units per row (8 / 4)

    const int tid  = threadIdx.x;
    const int w    = tid >> 6;
    const int lane = tid & 63;
    const int g    = lane >> 4;            // 0..3
    const int q16  = lane & 15;

    // 1024 blocks -> 8 XCDs x 8 bh x 16 q-blocks (bijective; bid%8 = XCD)
    const int xcd    = blockIdx.x & 7;
    const int within = blockIdx.x >> 3;    // 0..127
    const int bh     = xcd * 8 + (within >> 4);
    const int b      = bh >> 3, h = bh & 7;
    const int q0     = ((within & 15) * 4 + w) * 16;   // 16 q-rows per wave

    const u16* __restrict__ qbase = Qb + (size_t)bh * NN * D;
    const u16* __restrict__ kbase = Kb + (size_t)bh * NN * D;
    const u16* __restrict__ vbase = VT + (size_t)bh * 32 * D * 32;  // chunk-major
    const u32* __restrict__ brow  = bits + ((size_t)b * NN + q0 + q16) * 32;

    __shared__ alignas(16) char KsB[32 * 2 * D];   // [32 rows][D] bf16, swizzled
    __shared__ alignas(16) char VsB[D * 80];       // [D rows][40] bf16 (pad 8)

    // staging role (all threads active for D=128; split for D=64)
    bool doK, doV;
    int kRow = 0, kA = 0, vD = 0, vHalf = 0;
    if constexpr (D == 128) {
        doK = true; doV = true;
        kRow = tid >> 3; kA = tid & 7;     // 8 units/row, 32 rows
        vD = tid >> 1;  vHalf = tid & 1;   // 2 units/row, 128 rows
    } else {
        doK = (tid < 128); doV = !doK;
        kRow = tid >> 2; kA = tid & 3;     // 4 units/row
        const int vt = tid - 128;
        vD = vt >> 1;   vHalf = vt & 1;
    }

    // Q as B-fragment: col=q16=q, k = f*32 + g*8 + j
    bf16x8 qf[ND4];
#pragma unroll
    for (int f = 0; f < ND4; ++f)
        qf[f] = *(const bf16x8*)&qbase[(size_t)(q0 + q16) * D + f * 32 + g * 8];

    f32x4 acc[NDT];
#pragma unroll
    for (int dt = 0; dt < NDT; ++dt) acc[dt] = (f32x4)0.f;
    float l = 0.f;                         // per-lane partial for q=q16

    uint4 sk0, sk1, sv0, sv1;
    auto stage_load = [&](int ch) {
        if (doK) {
            const u16* src = kbase + (size_t)(ch * 32 + kRow) * D + kA * 16;
            sk0 = *(const uint4*)(src);
            sk1 = *(const uint4*)(src + 8);
        }
        if (doV) {
            const u16* src = vbase + ((size_t)ch * D + vD) * 32 + vHalf * 16;
            sv0 = *(const uint4*)(src);
            sv1 = *(const uint4*)(src + 8);
        }
    };
    auto stage_write = [&]() {
        if (doK) {
            char* kr = KsB + kRow * KROWB;
            *(uint4*)(kr + (((2 * kA)     ^ (kRow & 7)) * 16)) = sk0;
            *(uint4*)(kr + (((2 * kA + 1) ^ (kRow & 7)) * 16)) = sk1;
        }
        if (doV) {
            char* vr = VsB + vD * 80 + vHalf * 32;
            *(uint4*)(vr)      = sv0;
            *(uint4*)(vr + 16) = sv1;
        }
    };

    // prologue: stage chunk 0
    stage_load(0);
    stage_write();
    __syncthreads();

#pragma unroll 1
    for (int ch = 0; ch < 32; ++ch) {
        // issue next chunk's global loads early (latency hides under compute)
        if (ch + 1 < 32) stage_load(ch + 1);

        const u32 bw = brow[ch];

        // K A-fragments from swizzled LDS (row=kb*16+q16, granule f*4+g)
        bf16x8 kf[2][ND4];
#pragma unroll
        for (int kb = 0; kb < 2; ++kb)
#pragma unroll
            for (int f = 0; f < ND4; ++f)
                kf[kb][f] = *(const bf16x8*)
                    (KsB + (kb * 16 + q16) * KROWB + (((f * 4 + g) ^ (q16 & 7)) * 16));

        // QK^T: two independent chains
        f32x4 s0 = (f32x4)0.f, s1 = (f32x4)0.f;
#pragma unroll
        for (int f = 0; f < ND4; ++f) {
            s0 = __builtin_amdgcn_mfma_f32_16x16x32_bf16(kf[0][f], qf[f], s0, 0, 0, 0);
            s1 = __builtin_amdgcn_mfma_f32_16x16x32_bf16(kf[1][f], qf[f], s1, 0, 0, 0);
        }

        // V B-fragments from padded LDS (row=dt*16+q16, byte g*16)
        bf16x8 vf[NDT];
#pragma unroll
        for (int dt = 0; dt < NDT; ++dt)
            vf[dt] = *(const bf16x8*)(VsB + (dt * 16 + q16) * 80 + g * 16);

        // mask + exp2 + partial l; reg r of s[kb] is key 16kb+4g+r
        const u32 sh = bw >> (g * 4);
        float p0[4], p1[4];
#pragma unroll
        for (int r = 0; r < 4; ++r) {
            float a = s0[r] - (((sh >> r) & 1u)        ? 1.0e9f : 0.f);
            float c = s1[r] - (((sh >> (16 + r)) & 1u) ? 1.0e9f : 0.f);
            p0[r] = exp2f(a);
            p1[r] = exp2f(c);
        }
        l += ((p0[0] + p0[1]) + (p0[2] + p0[3]))
           + ((p1[0] + p1[1]) + (p1[2] + p1[3]));

        // P -> A-frag words (V pre-permuted: no cross-lane exchange)
        union { u32 u[4]; bf16x8 v; } pa;
        pa.u[0] = cvt_pk_bf16(p0[0], p0[1]);
        pa.u[1] = cvt_pk_bf16(p0[2], p0[3]);
        pa.u[2] = cvt_pk_bf16(p1[0], p1[1]);
        pa.u[3] = cvt_pk_bf16(p1[2], p1[3]);

        // PV: one K=32 A-frag covers the whole chunk
#pragma unroll
        for (int dt = 0; dt < NDT; ++dt)
            acc[dt] = __builtin_amdgcn_mfma_f32_16x16x32_bf16(pa.v, vf[dt], acc[dt], 0, 0, 0);

        __syncthreads();                   // all LDS reads of chunk ch done
        if (ch + 1 < 32) stage_write();    // (compiler inserts vmcnt)
        __syncthreads();                   // chunk ch+1 visible
    }

    // l: sum the 4 g-group partials for each q16 (lanes q16+16g)
    l += __shfl_xor(l, 16);
    l += __shfl_xor(l, 32);
    const float inv = 1.0f / l;            // valid on every lane for its q16

    // C layout: row=q=4g+r (regs), col=d=dt*16+q16
    float ivr[4];
#pragma unroll
    for (int r = 0; r < 4; ++r) ivr[r] = __shfl(inv, g * 4 + r);
#pragma unroll
    for (int dt = 0; dt < NDT; ++dt)
#pragma unroll
        for (int r = 0; r < 4; ++r) {
            const int q = q0 + g * 4 + r;
            O[(((size_t)b * NN + q) * NH + h) * D + dt * 16 + q16] = acc[dt][r] * ivr[r];
        }
}

// ---------------------------------------------------------------------------
// Output projection (fp32): thread owns 4 consecutive output cols (float4
// weight loads shared across row-groups), 1 row per thread from LDS.
// ---------------------------------------------------------------------------
template <int CIN, int COUT, int RB>
__global__ __launch_bounds__(256)
void wo_proj2(const float* __restrict__ Hin,
              const float* __restrict__ Wo,
              float* __restrict__ Hout) {
    constexpr int CG = COUT / 4;           // col groups (32 / 16)
    static_assert(256 / CG == RB, "one row per thread");
    const int r0  = blockIdx.x * RB;
    const int tid = threadIdx.x;
    const int cg  = tid % CG;
    const int rg  = tid / CG;

    __shared__ float xs[RB][CIN];
    for (int i = tid; i < RB * CIN / 4; i += 256) {
        const int rr = i / (CIN / 4), ff = (i % (CIN / 4)) * 4;
        *(float4*)&xs[rr][ff] = *(const float4*)&Hin[(size_t)(r0 + rr) * CIN + ff];
    }
    __syncthreads();

    const float* __restrict__ wp = Wo + 4 * cg;
    float a0 = 0.f, a1 = 0.f, a2 = 0.f, a3 = 0.f;
#pragma unroll 8
    for (int f = 0; f < CIN; ++f) {
        const float4 wv = *(const float4*)&wp[(size_t)f * COUT];
        const float xv = xs[rg][f];
        a0 = fmaf(xv, wv.x, a0);
        a1 = fmaf(xv, wv.y, a1);
        a2 = fmaf(xv, wv.z, a2);
        a3 = fmaf(xv, wv.w, a3);
    }
    float4 o; o.x = a0; o.y = a1; o.z = a2; o.w = a3;
    *(float4*)&Hout[(size_t)(r0 + rg) * COUT + 4 * cg] = o;
}

// ---------------------------------------------------------------------------
// Mean over N + 3-layer MLP. One block per batch element.
// ---------------------------------------------------------------------------
__global__ void pool_mlp(const float* __restrict__ H2,
                         const float* __restrict__ W1, const float* __restrict__ b1,
                         const float* __restrict__ W2, const float* __restrict__ b2,
                         const float* __restrict__ W3, const float* __restrict__ b3,
                         float* __restrict__ out) {
    const int b = blockIdx.x;
    const int tid = threadIdx.x;       // 256
    __shared__ float red[4][64];
    __shared__ float mean[64];
    __shared__ float h1[32];
    __shared__ float h2[16];

    const int o = tid & 63;
    const int g = tid >> 6;
    float acc = 0.f;
    for (int n = g; n < NN; n += 4) acc += H2[((size_t)b * NN + n) * 64 + o];
    red[g][o] = acc;
    __syncthreads();
    if (g == 0) mean[o] = (red[0][o] + red[1][o] + red[2][o] + red[3][o]) * (1.0f / 1024.0f);
    __syncthreads();

    if (tid < 32) {
        float a = b1[tid];
#pragma unroll
        for (int f = 0; f < 64; ++f) a = fmaf(mean[f], W1[f * 32 + tid], a);
        h1[tid] = fmaxf(a, 0.f);
    }
    __syncthreads();
    if (tid < 16) {
        float a = b2[tid];
#pragma unroll
        for (int f = 0; f < 32; ++f) a = fmaf(h1[f], W2[f * 16 + tid], a);
        h2[tid] = fmaxf(a, 0.f);
    }
    __syncthreads();
    if (tid == 0) {
        float a = b3[0];
#pragma unroll
        for (int f = 0; f < 16; ++f) a = fmaf(h2[f], W3[f], a);
        out[b] = a;
    }
}

// ---------------------------------------------------------------------------
extern "C" void kernel_launch(void* const* d_in, const int* in_sizes, int n_in,
                              void* d_out, int out_size, void* d_ws, size_t ws_size,
                              hipStream_t stream) {
    const float* X   = (const float*)d_in[0];
    const float* A   = (const float*)d_in[1];
    const float* Wq1 = (const float*)d_in[2];
    const float* Wk1 = (const float*)d_in[3];
    const float* Wv1 = (const float*)d_in[4];
    const float* Wo1 = (const float*)d_in[5];
    const float* Wq2 = (const float*)d_in[6];
    const float* Wk2 = (const float*)d_in[7];
    const float* Wv2 = (const float*)d_in[8];
    const float* Wo2 = (const float*)d_in[9];
    const float* W1  = (const float*)d_in[10];
    const float* b1  = (const float*)d_in[11];
    const float* W2  = (const float*)d_in[12];
    const float* b2  = (const float*)d_in[13];
    const float* W3  = (const float*)d_in[14];
    const float* b3  = (const float*)d_in[15];
    float* out = (float*)d_out;

    // workspace layout
    u32* bits = (u32*)d_ws;                       // 262144 u32 = 1MB
    u16* Qb1  = (u16*)(bits + 262144);            // 8M bf16 = 16MB
    u16* Kb1  = Qb1 + 8388608;
    u16* VT1  = Kb1 + 8388608;                    // chunk-major V
    float* ctx1 = (float*)(VT1 + 8388608);        // 8M f32 [B,N,1024]
    float* H1   = ctx1 + 8388608;                 // 1M f32 [B,N,128]
    u16* Qb2  = (u16*)(H1 + 1048576);             // 4M bf16
    u16* Kb2  = Qb2 + 4194304;
    u16* VT2  = Kb2 + 4194304;
    float* ctx2 = (float*)(VT2 + 4194304);        // 4M f32 [B,N,512]
    float* H2   = ctx2 + 4194304;                 // 0.5M f32 [B,N,64]

    const int ROWS = NB * NN;                     // 8192
    const float LOG2E = 1.4426950408889634f;

    mask_bits<<<ROWS, 256, 0, stream>>>(A, bits);

    // ----- layer 1 (D = 128) -----
    proj_qkv_bf<64, 1024, 128><<<ROWS / 16, 256, 0, stream>>>(
        X, Wq1, Wk1, Wv1, Qb1, Kb1, VT1, 0.08838834764831845f * LOG2E);
    attn_v9<128><<<1024, 256, 0, stream>>>(Qb1, Kb1, VT1, bits, ctx1);
    wo_proj2<1024, 128, 8><<<ROWS / 8, 256, 0, stream>>>(ctx1, Wo1, H1);

    // ----- layer 2 (D = 64) -----
    proj_qkv_bf<128, 512, 64><<<ROWS / 16, 256, 0, stream>>>(
        H1, Wq2, Wk2, Wv2, Qb2, Kb2, VT2, 0.125f * LOG2E);
    attn_v9<64><<<1024, 256, 0, stream>>>(Qb2, Kb2, VT2, bits, ctx2);
    wo_proj2<512, 64, 16><<<ROWS / 16, 256, 0, stream>>>(ctx2, Wo2, H2);

    // ----- pool + MLP -----
    pool_mlp<<<NB, 256, 0, stream>>>(H2, W1, b1, W2, b2, W3, b3, out);
}

// Round 12
// 337.261 us; speedup vs baseline: 2.2342x; 1.3289x over previous
//
#include <hip/hip_runtime.h>
#include <hip/hip_bf16.h>
#include <math.h>

// B=8, N=1024, F=64, HEADS=8, u1=128, u2=64
#define NB 8
#define NN 1024
#define NH 8

typedef __attribute__((ext_vector_type(8))) short bf16x8;
typedef __attribute__((ext_vector_type(4))) float f32x4;
typedef unsigned int u32;
typedef unsigned short u16;

__device__ __forceinline__ u16 f2bf(float f) {
    union { float f; u32 u; } v; v.f = f;
    const u32 u = v.u;
    return (u16)((u + 0x7fffu + ((u >> 16) & 1u)) >> 16);
}

// packed f32x2 -> bf16x2 (RTNE), dst.lo = lo, dst.hi = hi
__device__ __forceinline__ u32 cvt_pk_bf16(float lo, float hi) {
    u32 r;
    asm("v_cvt_pk_bf16_f32 %0, %1, %2" : "=v"(r) : "v"(lo), "v"(hi));
    return r;
}

// ---------------------------------------------------------------------------
// Mask bit-pack: A [B,N,N] f32 (0/1) -> bits [B*N, 32] u32 (bit=1 => masked)
// ---------------------------------------------------------------------------
__global__ __launch_bounds__(256) void mask_bits(const float* __restrict__ A,
                                                 u32* __restrict__ bits) {
    const int row = blockIdx.x;            // 0..B*N-1
    const int tid = threadIdx.x;
    const int lane = tid & 63;
    const float* __restrict__ ar = A + (size_t)row * NN;
#pragma unroll
    for (int it = 0; it < 4; ++it) {
        const int i = it * 256 + tid;
        const unsigned long long bal = __ballot(ar[i] != 0.0f);
        const int w0 = (it * 256 + (tid & ~63)) >> 5;
        if (lane == 0)  bits[(size_t)row * 32 + w0]     = (u32)bal;
        if (lane == 32) bits[(size_t)row * 32 + w0 + 1] = (u32)(bal >> 32);
    }
}

// ---------------------------------------------------------------------------
// Wo transpose+bf16: WoT[n][k] = bf16(Wo[k][n]).  Small, launch-once.
// ---------------------------------------------------------------------------
template <int CIN, int COUT>
__global__ __launch_bounds__(256)
void cvt_woT(const float* __restrict__ Wo, u16* __restrict__ WoT) {
    const int idx = blockIdx.x * 256 + threadIdx.x;   // n*CIN/8 + k8
    const int n  = idx / (CIN / 8);
    const int k0 = (idx % (CIN / 8)) * 8;
    u16 tmp[8];
#pragma unroll
    for (int j = 0; j < 8; ++j)
        tmp[j] = f2bf(Wo[(size_t)(k0 + j) * COUT + n]);
    *(uint4*)&WoT[(size_t)n * CIN + k0] = *(uint4*)tmp;
}

// ---------------------------------------------------------------------------
// Fused QKV projection -> bf16 outputs.
// Qb: [B,H,N,D] bf16 (pre-scaled), Kb: [B,H,N,D] bf16.
// VT: CHUNK-MAJOR [bh][ch=32][D][32keys''] bf16 where within each 32-key
// group key k sits at n'' = 8*((k>>2)&3) + (k&3) + 4*((k>>4)&1) -- so a 16B
// read at position 8g delivers keys 4g+(j&3)+16*(j>>2) in slot j, exactly
// P's natural post-QK^T key order for the 16x16x32 PV A-fragment (R9-verified).
// ---------------------------------------------------------------------------
template <int KIN, int HD, int D>
__global__ __launch_bounds__(256)
void proj_qkv_bf(const float* __restrict__ X,
                 const float* __restrict__ Wq,
                 const float* __restrict__ Wk,
                 const float* __restrict__ Wv,
                 u16* __restrict__ Qb,
                 u16* __restrict__ Kb,
                 u16* __restrict__ VT,
                 const float qscale) {
    constexpr int RB  = 16;
    constexpr int CPW = HD / 256;          // 4 (layer1) or 2 (layer2)
    const int r0  = blockIdx.x * RB;
    const int b   = r0 >> 10;
    const int n0  = r0 & 1023;             // multiple of 16
    const int tid = threadIdx.x;

    __shared__ float xs[RB][KIN];
    for (int i = tid; i < RB * KIN / 4; i += 256) {
        const int rr = i / (KIN / 4), ff = (i % (KIN / 4)) * 4;
        *(float4*)&xs[rr][ff] = *(const float4*)&X[(size_t)(r0 + rr) * KIN + ff];
    }
    __syncthreads();

    const int c0 = CPW * tid;
    const int h  = c0 / D;
    const int d0 = c0 % D;
    const int bh = b * NH + h;

    const float* Ws[3] = {Wq, Wk, Wv};
#pragma unroll 1
    for (int w = 0; w < 3; ++w) {
        const float* __restrict__ W = Ws[w];
        float acc[RB][CPW];
#pragma unroll
        for (int rr = 0; rr < RB; ++rr)
#pragma unroll
            for (int k = 0; k < CPW; ++k) acc[rr][k] = 0.f;

#pragma unroll 4
        for (int f = 0; f < KIN; ++f) {
            float wv[CPW];
            if constexpr (CPW == 4) {
                const float4 t = *(const float4*)&W[(size_t)f * HD + c0];
                wv[0] = t.x; wv[1] = t.y; wv[2] = t.z; wv[3] = t.w;
            } else {
                const float2 t = *(const float2*)&W[(size_t)f * HD + c0];
                wv[0] = t.x; wv[1] = t.y;
            }
#pragma unroll
            for (int rr = 0; rr < RB; ++rr) {
                const float xv = xs[rr][f];
#pragma unroll
                for (int k = 0; k < CPW; ++k) acc[rr][k] = fmaf(xv, wv[k], acc[rr][k]);
            }
        }

        if (w == 2) {
            // V store, chunk-major + 32-group permutation.
            const int ch  = n0 >> 5;
            const int grp = (n0 >> 4) & 1;
#pragma unroll
            for (int k = 0; k < CPW; ++k) {
                u32* dst = (u32*)&VT[(((size_t)bh * 32 + ch) * D + d0 + k) * 32]
                           + 2 * grp;
                uint2 w0, w1, w2, w3;
                w0.x = (u32)f2bf(acc[0][k])  | ((u32)f2bf(acc[1][k])  << 16);
                w0.y = (u32)f2bf(acc[2][k])  | ((u32)f2bf(acc[3][k])  << 16);
                w1.x = (u32)f2bf(acc[4][k])  | ((u32)f2bf(acc[5][k])  << 16);
                w1.y = (u32)f2bf(acc[6][k])  | ((u32)f2bf(acc[7][k])  << 16);
                w2.x = (u32)f2bf(acc[8][k])  | ((u32)f2bf(acc[9][k])  << 16);
                w2.y = (u32)f2bf(acc[10][k]) | ((u32)f2bf(acc[11][k]) << 16);
                w3.x = (u32)f2bf(acc[12][k]) | ((u32)f2bf(acc[13][k]) << 16);
                w3.y = (u32)f2bf(acc[14][k]) | ((u32)f2bf(acc[15][k]) << 16);
                *(uint2*)(dst + 0)  = w0;
                *(uint2*)(dst + 4)  = w1;
                *(uint2*)(dst + 8)  = w2;
                *(uint2*)(dst + 12) = w3;
            }
        } else {
            u16* __restrict__ O = (w == 0) ? Qb : Kb;
            const float sc = (w == 0) ? qscale : 1.0f;
#pragma unroll
            for (int rr = 0; rr < RB; ++rr) {
                u16* dst = &O[((size_t)bh * NN + (n0 + rr)) * D + d0];
                if constexpr (CPW == 4) {
                    uint2 v;
                    v.x = (u32)f2bf(acc[rr][0] * sc) | ((u32)f2bf(acc[rr][1] * sc) << 16);
                    v.y = (u32)f2bf(acc[rr][2] * sc) | ((u32)f2bf(acc[rr][3] * sc) << 16);
                    *(uint2*)dst = v;
                } else {
                    u32 v = (u32)f2bf(acc[rr][0] * sc) | ((u32)f2bf(acc[rr][1] * sc) << 16);
                    *(u32*)dst = v;
                }
            }
        }
    }
}

// ---------------------------------------------------------------------------
// MFMA flash attention v9b: LDS-staged K/V shared by 4 waves (64 q-rows),
// 2-phase schedule with async-stage split.  Body math = v8 (verified).
// Epilogue now writes ctx as BF16 [B,N,H*D] (feeds the MFMA Wo GEMM).
// ---------------------------------------------------------------------------
template <int D>
__global__ __launch_bounds__(256, 2)
void attn_v9(const u16* __restrict__ Qb,
             const u16* __restrict__ Kb,
             const u16* __restrict__ VT,
             const u32* __restrict__ bits,
             u16* __restrict__ Ob) {
    constexpr int ND4 = D / 32;            // QK k-steps per kb (4 / 2)
    constexpr int NDT = D / 16;            // PV d-tiles (8 / 4)
    constexpr int KROWB = 2 * D;           // K LDS row bytes (256 / 128)

    const int tid  = threadIdx.x;
    const int w    = tid >> 6;
    const int lane = tid & 63;
    const int g    = lane >> 4;            // 0..3
    const int q16  = lane & 15;

    // 1024 blocks -> 8 XCDs x 8 bh x 16 q-blocks (bijective; bid%8 = XCD)
    const int xcd    = blockIdx.x & 7;
    const int within = blockIdx.x >> 3;    // 0..127
    const int bh     = xcd * 8 + (within >> 4);
    const int b      = bh >> 3, h = bh & 7;
    const int q0     = ((within & 15) * 4 + w) * 16;   // 16 q-rows per wave

    const u16* __restrict__ qbase = Qb + (size_t)bh * NN * D;
    const u16* __restrict__ kbase = Kb + (size_t)bh * NN * D;
    const u16* __restrict__ vbase = VT + (size_t)bh * 32 * D * 32;  // chunk-major
    const u32* __restrict__ brow  = bits + ((size_t)b * NN + q0 + q16) * 32;

    __shared__ alignas(16) char KsB[32 * 2 * D];   // [32 rows][D] bf16, swizzled
    __shared__ alignas(16) char VsB[D * 80];       // [D rows][40] bf16 (pad 8)

    bool doK, doV;
    int kRow = 0, kA = 0, vD = 0, vHalf = 0;
    if constexpr (D == 128) {
        doK = true; doV = true;
        kRow = tid >> 3; kA = tid & 7;
        vD = tid >> 1;  vHalf = tid & 1;
    } else {
        doK = (tid < 128); doV = !doK;
        kRow = tid >> 2; kA = tid & 3;
        const int vt = tid - 128;
        vD = vt >> 1;   vHalf = vt & 1;
    }

    bf16x8 qf[ND4];
#pragma unroll
    for (int f = 0; f < ND4; ++f)
        qf[f] = *(const bf16x8*)&qbase[(size_t)(q0 + q16) * D + f * 32 + g * 8];

    f32x4 acc[NDT];
#pragma unroll
    for (int dt = 0; dt < NDT; ++dt) acc[dt] = (f32x4)0.f;
    float l = 0.f;

    uint4 sk0, sk1, sv0, sv1;
    auto stage_load = [&](int ch) {
        if (doK) {
            const u16* src = kbase + (size_t)(ch * 32 + kRow) * D + kA * 16;
            sk0 = *(const uint4*)(src);
            sk1 = *(const uint4*)(src + 8);
        }
        if (doV) {
            const u16* src = vbase + ((size_t)ch * D + vD) * 32 + vHalf * 16;
            sv0 = *(const uint4*)(src);
            sv1 = *(const uint4*)(src + 8);
        }
    };
    auto stage_write = [&]() {
        if (doK) {
            char* kr = KsB + kRow * KROWB;
            *(uint4*)(kr + (((2 * kA)     ^ (kRow & 7)) * 16)) = sk0;
            *(uint4*)(kr + (((2 * kA + 1) ^ (kRow & 7)) * 16)) = sk1;
        }
        if (doV) {
            char* vr = VsB + vD * 80 + vHalf * 32;
            *(uint4*)(vr)      = sv0;
            *(uint4*)(vr + 16) = sv1;
        }
    };

    stage_load(0);
    stage_write();
    __syncthreads();

#pragma unroll 1
    for (int ch = 0; ch < 32; ++ch) {
        if (ch + 1 < 32) stage_load(ch + 1);

        const u32 bw = brow[ch];

        bf16x8 kf[2][ND4];
#pragma unroll
        for (int kb = 0; kb < 2; ++kb)
#pragma unroll
            for (int f = 0; f < ND4; ++f)
                kf[kb][f] = *(const bf16x8*)
                    (KsB + (kb * 16 + q16) * KROWB + (((f * 4 + g) ^ (q16 & 7)) * 16));

        f32x4 s0 = (f32x4)0.f, s1 = (f32x4)0.f;
#pragma unroll
        for (int f = 0; f < ND4; ++f) {
            s0 = __builtin_amdgcn_mfma_f32_16x16x32_bf16(kf[0][f], qf[f], s0, 0, 0, 0);
            s1 = __builtin_amdgcn_mfma_f32_16x16x32_bf16(kf[1][f], qf[f], s1, 0, 0, 0);
        }

        bf16x8 vf[NDT];
#pragma unroll
        for (int dt = 0; dt < NDT; ++dt)
            vf[dt] = *(const bf16x8*)(VsB + (dt * 16 + q16) * 80 + g * 16);

        const u32 sh = bw >> (g * 4);
        float p0[4], p1[4];
#pragma unroll
        for (int r = 0; r < 4; ++r) {
            float a = s0[r] - (((sh >> r) & 1u)        ? 1.0e9f : 0.f);
            float c = s1[r] - (((sh >> (16 + r)) & 1u) ? 1.0e9f : 0.f);
            p0[r] = exp2f(a);
            p1[r] = exp2f(c);
        }
        l += ((p0[0] + p0[1]) + (p0[2] + p0[3]))
           + ((p1[0] + p1[1]) + (p1[2] + p1[3]));

        union { u32 u[4]; bf16x8 v; } pa;
        pa.u[0] = cvt_pk_bf16(p0[0], p0[1]);
        pa.u[1] = cvt_pk_bf16(p0[2], p0[3]);
        pa.u[2] = cvt_pk_bf16(p1[0], p1[1]);
        pa.u[3] = cvt_pk_bf16(p1[2], p1[3]);

#pragma unroll
        for (int dt = 0; dt < NDT; ++dt)
            acc[dt] = __builtin_amdgcn_mfma_f32_16x16x32_bf16(pa.v, vf[dt], acc[dt], 0, 0, 0);

        __syncthreads();
        if (ch + 1 < 32) stage_write();
        __syncthreads();
    }

    l += __shfl_xor(l, 16);
    l += __shfl_xor(l, 32);
    const float inv = 1.0f / l;

    float ivr[4];
#pragma unroll
    for (int r = 0; r < 4; ++r) ivr[r] = __shfl(inv, g * 4 + r);
#pragma unroll
    for (int dt = 0; dt < NDT; ++dt)
#pragma unroll
        for (int r = 0; r < 4; ++r) {
            const int q = q0 + g * 4 + r;
            Ob[(((size_t)b * NN + q) * NH + h) * D + dt * 16 + q16] =
                f2bf(acc[dt][r] * ivr[r]);
        }
}

// ---------------------------------------------------------------------------
// Output projection via MFMA: H[rows,COUT] f32 = ctxb[rows,CIN]bf16 @ Wo.
// WoT: [COUT][CIN] bf16 (transposed).  Block = 16 rows x 4 waves; wave owns
// COUT/4 output cols (NTW n-tiles of 16).  All operand loads are contiguous
// 16B, L1/L2-hot.  A row=lane&15 -> ctx row; B col=lane&15 -> n; k=g*8+j.
// C: col=q16=n, row=4g+r.
// ---------------------------------------------------------------------------
template <int CIN, int COUT>
__global__ __launch_bounds__(256)
void wo_mfma(const u16* __restrict__ ctxb,
             const u16* __restrict__ WoT,
             float* __restrict__ H) {
    constexpr int NTW = COUT / 64;         // n-tiles per wave (2 / 1)
    const int tid  = threadIdx.x;
    const int w    = tid >> 6;
    const int lane = tid & 63;
    const int g    = lane >> 4;
    const int q16  = lane & 15;
    const int r0   = blockIdx.x * 16;

    f32x4 acc[NTW];
#pragma unroll
    for (int nt = 0; nt < NTW; ++nt) acc[nt] = (f32x4)0.f;

    const u16* __restrict__ arow = ctxb + (size_t)(r0 + q16) * CIN + g * 8;

#pragma unroll 4
    for (int k0 = 0; k0 < CIN; k0 += 32) {
        const bf16x8 af = *(const bf16x8*)(arow + k0);
#pragma unroll
        for (int nt = 0; nt < NTW; ++nt) {
            const int n = (w * NTW + nt) * 16 + q16;
            const bf16x8 wf = *(const bf16x8*)&WoT[(size_t)n * CIN + k0 + g * 8];
            acc[nt] = __builtin_amdgcn_mfma_f32_16x16x32_bf16(af, wf, acc[nt], 0, 0, 0);
        }
    }

#pragma unroll
    for (int nt = 0; nt < NTW; ++nt)
#pragma unroll
        for (int r = 0; r < 4; ++r)
            H[(size_t)(r0 + 4 * g + r) * COUT + (w * NTW + nt) * 16 + q16] = acc[nt][r];
}

// ---------------------------------------------------------------------------
// Mean over N + 3-layer MLP. One block per batch element.
// ---------------------------------------------------------------------------
__global__ void pool_mlp(const float* __restrict__ H2,
                         const float* __restrict__ W1, const float* __restrict__ b1,
                         const float* __restrict__ W2, const float* __restrict__ b2,
                         const float* __restrict__ W3, const float* __restrict__ b3,
                         float* __restrict__ out) {
    const int b = blockIdx.x;
    const int tid = threadIdx.x;       // 256
    __shared__ float red[4][64];
    __shared__ float mean[64];
    __shared__ float h1[32];
    __shared__ float h2[16];

    const int o = tid & 63;
    const int g = tid >> 6;
    float acc = 0.f;
    for (int n = g; n < NN; n += 4) acc += H2[((size_t)b * NN + n) * 64 + o];
    red[g][o] = acc;
    __syncthreads();
    if (g == 0) mean[o] = (red[0][o] + red[1][o] + red[2][o] + red[3][o]) * (1.0f / 1024.0f);
    __syncthreads();

    if (tid < 32) {
        float a = b1[tid];
#pragma unroll
        for (int f = 0; f < 64; ++f) a = fmaf(mean[f], W1[f * 32 + tid], a);
        h1[tid] = fmaxf(a, 0.f);
    }
    __syncthreads();
    if (tid < 16) {
        float a = b2[tid];
#pragma unroll
        for (int f = 0; f < 32; ++f) a = fmaf(h1[f], W2[f * 16 + tid], a);
        h2[tid] = fmaxf(a, 0.f);
    }
    __syncthreads();
    if (tid == 0) {
        float a = b3[0];
#pragma unroll
        for (int f = 0; f < 16; ++f) a = fmaf(h2[f], W3[f], a);
        out[b] = a;
    }
}

// ---------------------------------------------------------------------------
extern "C" void kernel_launch(void* const* d_in, const int* in_sizes, int n_in,
                              void* d_out, int out_size, void* d_ws, size_t ws_size,
                              hipStream_t stream) {
    const float* X   = (const float*)d_in[0];
    const float* A   = (const float*)d_in[1];
    const float* Wq1 = (const float*)d_in[2];
    const float* Wk1 = (const float*)d_in[3];
    const float* Wv1 = (const float*)d_in[4];
    const float* Wo1 = (const float*)d_in[5];
    const float* Wq2 = (const float*)d_in[6];
    const float* Wk2 = (const float*)d_in[7];
    const float* Wv2 = (const float*)d_in[8];
    const float* Wo2 = (const float*)d_in[9];
    const float* W1  = (const float*)d_in[10];
    const float* b1  = (const float*)d_in[11];
    const float* W2  = (const float*)d_in[12];
    const float* b2  = (const float*)d_in[13];
    const float* W3  = (const float*)d_in[14];
    const float* b3  = (const float*)d_in[15];
    float* out = (float*)d_out;

    // workspace layout
    u32* bits  = (u32*)d_ws;                       // 1 MB
    u16* base  = (u16*)(bits + 262144);
    u16* Qb1   = base;                 base += 8388608;   // 16 MB
    u16* Kb1   = base;                 base += 8388608;
    u16* VT1   = base;                 base += 8388608;   // chunk-major V
    u16* ctx1b = base;                 base += 8388608;   // bf16 ctx [B,N,1024]
    u16* WoT1  = base;                 base += 131072;    // [128][1024]
    u16* Qb2   = base;                 base += 4194304;
    u16* Kb2   = base;                 base += 4194304;
    u16* VT2   = base;                 base += 4194304;
    u16* ctx2b = base;                 base += 4194304;   // bf16 ctx [B,N,512]
    u16* WoT2  = base;                 base += 32768;     // [64][512]
    float* H1  = (float*)base;                            // 4 MB f32 [B,N,128]
    float* H2  = H1 + 1048576;                            // 2 MB f32 [B,N,64]

    const int ROWS = NB * NN;                     // 8192
    const float LOG2E = 1.4426950408889634f;

    mask_bits<<<ROWS, 256, 0, stream>>>(A, bits);
    cvt_woT<1024, 128><<<128 * 1024 / 8 / 256, 256, 0, stream>>>(Wo1, WoT1);
    cvt_woT<512, 64><<<64 * 512 / 8 / 256, 256, 0, stream>>>(Wo2, WoT2);

    // ----- layer 1 (D = 128) -----
    proj_qkv_bf<64, 1024, 128><<<ROWS / 16, 256, 0, stream>>>(
        X, Wq1, Wk1, Wv1, Qb1, Kb1, VT1, 0.08838834764831845f * LOG2E);
    attn_v9<128><<<1024, 256, 0, stream>>>(Qb1, Kb1, VT1, bits, ctx1b);
    wo_mfma<1024, 128><<<ROWS / 16, 256, 0, stream>>>(ctx1b, WoT1, H1);

    // ----- layer 2 (D = 64) -----
    proj_qkv_bf<128, 512, 64><<<ROWS / 16, 256, 0, stream>>>(
        H1, Wq2, Wk2, Wv2, Qb2, Kb2, VT2, 0.125f * LOG2E);
    attn_v9<64><<<1024, 256, 0, stream>>>(Qb2, Kb2, VT2, bits, ctx2b);
    wo_mfma<512, 64><<<ROWS / 16, 256, 0, stream>>>(ctx2b, WoT2, H2);

    // ----- pool + MLP -----
    pool_mlp<<<NB, 256, 0, stream>>>(H2, W1, b1, W2, b2, W3, b3, out);
}

// Round 13
// 277.608 us; speedup vs baseline: 2.7143x; 1.2149x over previous
//
#include <hip/hip_runtime.h>
#include <hip/hip_bf16.h>
#include <math.h>

// B=8, N=1024, F=64, HEADS=8, u1=128, u2=64
#define NB 8
#define NN 1024
#define NH 8

typedef __attribute__((ext_vector_type(8))) short bf16x8;
typedef __attribute__((ext_vector_type(4))) float f32x4;
typedef unsigned int u32;
typedef unsigned short u16;

__device__ __forceinline__ u16 f2bf(float f) {
    union { float f; u32 u; } v; v.f = f;
    const u32 u = v.u;
    return (u16)((u + 0x7fffu + ((u >> 16) & 1u)) >> 16);
}

// packed f32x2 -> bf16x2 (RTNE), dst.lo = lo, dst.hi = hi
__device__ __forceinline__ u32 cvt_pk_bf16(float lo, float hi) {
    u32 r;
    asm("v_cvt_pk_bf16_f32 %0, %1, %2" : "=v"(r) : "v"(lo), "v"(hi));
    return r;
}

// ---------------------------------------------------------------------------
// Mask bit-pack: A [B,N,N] f32 (0/1) -> bits [B*N, 32] u32 (bit=1 => masked)
// ---------------------------------------------------------------------------
__global__ __launch_bounds__(256) void mask_bits(const float* __restrict__ A,
                                                 u32* __restrict__ bits) {
    const int row = blockIdx.x;            // 0..B*N-1
    const int tid = threadIdx.x;
    const int lane = tid & 63;
    const float* __restrict__ ar = A + (size_t)row * NN;
#pragma unroll
    for (int it = 0; it < 4; ++it) {
        const int i = it * 256 + tid;
        const unsigned long long bal = __ballot(ar[i] != 0.0f);
        const int w0 = (it * 256 + (tid & ~63)) >> 5;
        if (lane == 0)  bits[(size_t)row * 32 + w0]     = (u32)bal;
        if (lane == 32) bits[(size_t)row * 32 + w0 + 1] = (u32)(bal >> 32);
    }
}

// ---------------------------------------------------------------------------
// f32 -> bf16 vector convert (8 elems/thread).
// ---------------------------------------------------------------------------
__global__ __launch_bounds__(256)
void cvt_bf16(const float* __restrict__ in, u16* __restrict__ out) {
    const int i = blockIdx.x * 256 + threadIdx.x;
    const float4 a = ((const float4*)in)[2 * i];
    const float4 b = ((const float4*)in)[2 * i + 1];
    u16 t[8] = {f2bf(a.x), f2bf(a.y), f2bf(a.z), f2bf(a.w),
                f2bf(b.x), f2bf(b.y), f2bf(b.z), f2bf(b.w)};
    ((uint4*)out)[i] = *(uint4*)t;
}

// ---------------------------------------------------------------------------
// QKV weight transpose+bf16: WT[c][f] over c in [0,3*HD) = {Wq|Wk|Wv}[f][c%HD]
// ---------------------------------------------------------------------------
template <int KIN, int HD>
__global__ __launch_bounds__(256)
void cvt_qkvT(const float* __restrict__ Wq, const float* __restrict__ Wk,
              const float* __restrict__ Wv, u16* __restrict__ WT) {
    const int idx = blockIdx.x * 256 + threadIdx.x;   // c*(KIN/8) + f8
    const int c  = idx / (KIN / 8);
    const int f0 = (idx % (KIN / 8)) * 8;
    const float* __restrict__ W = (c < HD) ? Wq : (c < 2 * HD) ? Wk : Wv;
    const int cc = c % HD;
    u16 tmp[8];
#pragma unroll
    for (int j = 0; j < 8; ++j)
        tmp[j] = f2bf(W[(size_t)(f0 + j) * HD + cc]);
    *(uint4*)&WT[(size_t)c * KIN + f0] = *(uint4*)tmp;
}

// ---------------------------------------------------------------------------
// Wo transpose+bf16: WoT[n][k] = bf16(Wo[k][n]).
// ---------------------------------------------------------------------------
template <int CIN, int COUT>
__global__ __launch_bounds__(256)
void cvt_woT(const float* __restrict__ Wo, u16* __restrict__ WoT) {
    const int idx = blockIdx.x * 256 + threadIdx.x;   // n*CIN/8 + k8
    const int n  = idx / (CIN / 8);
    const int k0 = (idx % (CIN / 8)) * 8;
    u16 tmp[8];
#pragma unroll
    for (int j = 0; j < 8; ++j)
        tmp[j] = f2bf(Wo[(size_t)(k0 + j) * COUT + n]);
    *(uint4*)&WoT[(size_t)n * CIN + k0] = *(uint4*)tmp;
}

// ---------------------------------------------------------------------------
// MFMA QKV projection.  Xb: [rows][KIN] bf16.  WT: [3*HD][KIN] bf16.
// Block = 16 rows x 4 waves; wave handles n-tiles w+4i (16 channels each).
// C layout (verified): col=q16=channel, row=4g+r=row index.
// Outputs: Qb [bh][n][D] (x qscale), Kb same, VT chunk-major permuted
// [bh][ch][D][32''] with n'' = 8g + r + 4*grp for this 16-row tile
// (same R9-verified permutation: a 16B read at 8g gives P's key order).
// ---------------------------------------------------------------------------
template <int KIN, int HD, int D>
__global__ __launch_bounds__(256)
void proj_mfma(const u16* __restrict__ Xb,
               const u16* __restrict__ WT,
               u16* __restrict__ Qb,
               u16* __restrict__ Kb,
               u16* __restrict__ VT,
               const float qscale) {
    constexpr int NKT = KIN / 32;          // k-steps (2 / 4)
    constexpr int NTW = (3 * HD / 16) / 4; // n-tiles per wave (48 / 24)

    const int tid  = threadIdx.x;
    const int w    = tid >> 6;
    const int lane = tid & 63;
    const int g    = lane >> 4;
    const int q16  = lane & 15;
    const int r0   = blockIdx.x * 16;
    const int b    = r0 >> 10;
    const int n0   = r0 & 1023;
    const int ch   = n0 >> 5;
    const int grp  = (n0 >> 4) & 1;

    // A-fragments: X rows (row=q16 -> r0+q16, k = t*32+g*8+j)
    bf16x8 af[NKT];
#pragma unroll
    for (int t = 0; t < NKT; ++t)
        af[t] = *(const bf16x8*)&Xb[(size_t)(r0 + q16) * KIN + t * 32 + g * 8];

#pragma unroll 1
    for (int i = 0; i < NTW; ++i) {
        const int nt = w + 4 * i;
        const int c0 = nt * 16;
        f32x4 acc = (f32x4)0.f;
#pragma unroll
        for (int t = 0; t < NKT; ++t) {
            const bf16x8 wf = *(const bf16x8*)&WT[(size_t)(c0 + q16) * KIN + t * 32 + g * 8];
            acc = __builtin_amdgcn_mfma_f32_16x16x32_bf16(af[t], wf, acc, 0, 0, 0);
        }

        const int wcl = c0 / HD;           // 0=Q 1=K 2=V (wave-uniform)
        const int cc  = c0 % HD;
        const int h   = cc / D;
        const int d0  = cc % D;            // multiple of 16
        const int bh  = b * NH + h;

        if (wcl == 2) {
            // V: chunk-major + permuted; 4 consecutive u16 per lane
            u16 tmp[4];
#pragma unroll
            for (int r = 0; r < 4; ++r) tmp[r] = f2bf(acc[r]);
            *(uint2*)&VT[(((size_t)bh * 32 + ch) * D + d0 + q16) * 32
                         + 8 * g + 4 * grp] = *(uint2*)tmp;
        } else {
            u16* __restrict__ O = wcl ? Kb : Qb;
            const float sc = wcl ? 1.0f : qscale;
#pragma unroll
            for (int r = 0; r < 4; ++r)
                O[((size_t)bh * NN + n0 + 4 * g + r) * D + d0 + q16] = f2bf(acc[r] * sc);
        }
    }
}

// ---------------------------------------------------------------------------
// MFMA flash attention v9b: LDS-staged K/V shared by 4 waves (64 q-rows),
// 2-phase schedule with async-stage split.  Body math = v8 (verified).
// Epilogue writes ctx as BF16 [B,N,H*D].
// ---------------------------------------------------------------------------
template <int D>
__global__ __launch_bounds__(256, 2)
void attn_v9(const u16* __restrict__ Qb,
             const u16* __restrict__ Kb,
             const u16* __restrict__ VT,
             const u32* __restrict__ bits,
             u16* __restrict__ Ob) {
    constexpr int ND4 = D / 32;            // QK k-steps per kb (4 / 2)
    constexpr int NDT = D / 16;            // PV d-tiles (8 / 4)
    constexpr int KROWB = 2 * D;           // K LDS row bytes (256 / 128)

    const int tid  = threadIdx.x;
    const int w    = tid >> 6;
    const int lane = tid & 63;
    const int g    = lane >> 4;            // 0..3
    const int q16  = lane & 15;

    // 1024 blocks -> 8 XCDs x 8 bh x 16 q-blocks (bijective; bid%8 = XCD)
    const int xcd    = blockIdx.x & 7;
    const int within = blockIdx.x >> 3;    // 0..127
    const int bh     = xcd * 8 + (within >> 4);
    const int b      = bh >> 3, h = bh & 7;
    const int q0     = ((within & 15) * 4 + w) * 16;   // 16 q-rows per wave

    const u16* __restrict__ qbase = Qb + (size_t)bh * NN * D;
    const u16* __restrict__ kbase = Kb + (size_t)bh * NN * D;
    const u16* __restrict__ vbase = VT + (size_t)bh * 32 * D * 32;  // chunk-major
    const u32* __restrict__ brow  = bits + ((size_t)b * NN + q0 + q16) * 32;

    __shared__ alignas(16) char KsB[32 * 2 * D];   // [32 rows][D] bf16, swizzled
    __shared__ alignas(16) char VsB[D * 80];       // [D rows][40] bf16 (pad 8)

    bool doK, doV;
    int kRow = 0, kA = 0, vD = 0, vHalf = 0;
    if constexpr (D == 128) {
        doK = true; doV = true;
        kRow = tid >> 3; kA = tid & 7;
        vD = tid >> 1;  vHalf = tid & 1;
    } else {
        doK = (tid < 128); doV = !doK;
        kRow = tid >> 2; kA = tid & 3;
        const int vt = tid - 128;
        vD = vt >> 1;   vHalf = vt & 1;
    }

    bf16x8 qf[ND4];
#pragma unroll
    for (int f = 0; f < ND4; ++f)
        qf[f] = *(const bf16x8*)&qbase[(size_t)(q0 + q16) * D + f * 32 + g * 8];

    f32x4 acc[NDT];
#pragma unroll
    for (int dt = 0; dt < NDT; ++dt) acc[dt] = (f32x4)0.f;
    float l = 0.f;

    uint4 sk0, sk1, sv0, sv1;
    auto stage_load = [&](int ch) {
        if (doK) {
            const u16* src = kbase + (size_t)(ch * 32 + kRow) * D + kA * 16;
            sk0 = *(const uint4*)(src);
            sk1 = *(const uint4*)(src + 8);
        }
        if (doV) {
            const u16* src = vbase + ((size_t)ch * D + vD) * 32 + vHalf * 16;
            sv0 = *(const uint4*)(src);
            sv1 = *(const uint4*)(src + 8);
        }
    };
    auto stage_write = [&]() {
        if (doK) {
            char* kr = KsB + kRow * KROWB;
            *(uint4*)(kr + (((2 * kA)     ^ (kRow & 7)) * 16)) = sk0;
            *(uint4*)(kr + (((2 * kA + 1) ^ (kRow & 7)) * 16)) = sk1;
        }
        if (doV) {
            char* vr = VsB + vD * 80 + vHalf * 32;
            *(uint4*)(vr)      = sv0;
            *(uint4*)(vr + 16) = sv1;
        }
    };

    stage_load(0);
    stage_write();
    __syncthreads();

#pragma unroll 1
    for (int ch = 0; ch < 32; ++ch) {
        if (ch + 1 < 32) stage_load(ch + 1);

        const u32 bw = brow[ch];

        bf16x8 kf[2][ND4];
#pragma unroll
        for (int kb = 0; kb < 2; ++kb)
#pragma unroll
            for (int f = 0; f < ND4; ++f)
                kf[kb][f] = *(const bf16x8*)
                    (KsB + (kb * 16 + q16) * KROWB + (((f * 4 + g) ^ (q16 & 7)) * 16));

        f32x4 s0 = (f32x4)0.f, s1 = (f32x4)0.f;
#pragma unroll
        for (int f = 0; f < ND4; ++f) {
            s0 = __builtin_amdgcn_mfma_f32_16x16x32_bf16(kf[0][f], qf[f], s0, 0, 0, 0);
            s1 = __builtin_amdgcn_mfma_f32_16x16x32_bf16(kf[1][f], qf[f], s1, 0, 0, 0);
        }

        bf16x8 vf[NDT];
#pragma unroll
        for (int dt = 0; dt < NDT; ++dt)
            vf[dt] = *(const bf16x8*)(VsB + (dt * 16 + q16) * 80 + g * 16);

        const u32 sh = bw >> (g * 4);
        float p0[4], p1[4];
#pragma unroll
        for (int r = 0; r < 4; ++r) {
            float a = s0[r] - (((sh >> r) & 1u)        ? 1.0e9f : 0.f);
            float c = s1[r] - (((sh >> (16 + r)) & 1u) ? 1.0e9f : 0.f);
            p0[r] = exp2f(a);
            p1[r] = exp2f(c);
        }
        l += ((p0[0] + p0[1]) + (p0[2] + p0[3]))
           + ((p1[0] + p1[1]) + (p1[2] + p1[3]));

        union { u32 u[4]; bf16x8 v; } pa;
        pa.u[0] = cvt_pk_bf16(p0[0], p0[1]);
        pa.u[1] = cvt_pk_bf16(p0[2], p0[3]);
        pa.u[2] = cvt_pk_bf16(p1[0], p1[1]);
        pa.u[3] = cvt_pk_bf16(p1[2], p1[3]);

#pragma unroll
        for (int dt = 0; dt < NDT; ++dt)
            acc[dt] = __builtin_amdgcn_mfma_f32_16x16x32_bf16(pa.v, vf[dt], acc[dt], 0, 0, 0);

        __syncthreads();
        if (ch + 1 < 32) stage_write();
        __syncthreads();
    }

    l += __shfl_xor(l, 16);
    l += __shfl_xor(l, 32);
    const float inv = 1.0f / l;

    float ivr[4];
#pragma unroll
    for (int r = 0; r < 4; ++r) ivr[r] = __shfl(inv, g * 4 + r);
#pragma unroll
    for (int dt = 0; dt < NDT; ++dt)
#pragma unroll
        for (int r = 0; r < 4; ++r) {
            const int q = q0 + g * 4 + r;
            Ob[(((size_t)b * NN + q) * NH + h) * D + dt * 16 + q16] =
                f2bf(acc[dt][r] * ivr[r]);
        }
}

// ---------------------------------------------------------------------------
// Output projection via MFMA: out[rows,COUT] = ctxb[rows,CIN]bf16 @ Wo.
// BF16OUT selects bf16 (feeds next proj) or f32 (feeds pool) output.
// ---------------------------------------------------------------------------
template <int CIN, int COUT, bool BF16OUT>
__global__ __launch_bounds__(256)
void wo_mfma(const u16* __restrict__ ctxb,
             const u16* __restrict__ WoT,
             void* __restrict__ Hout) {
    constexpr int NTW = COUT / 64;         // n-tiles per wave (2 / 1)
    const int tid  = threadIdx.x;
    const int w    = tid >> 6;
    const int lane = tid & 63;
    const int g    = lane >> 4;
    const int q16  = lane & 15;
    const int r0   = blockIdx.x * 16;

    f32x4 acc[NTW];
#pragma unroll
    for (int nt = 0; nt < NTW; ++nt) acc[nt] = (f32x4)0.f;

    const u16* __restrict__ arow = ctxb + (size_t)(r0 + q16) * CIN + g * 8;

#pragma unroll 4
    for (int k0 = 0; k0 < CIN; k0 += 32) {
        const bf16x8 af = *(const bf16x8*)(arow + k0);
#pragma unroll
        for (int nt = 0; nt < NTW; ++nt) {
            const int n = (w * NTW + nt) * 16 + q16;
            const bf16x8 wf = *(const bf16x8*)&WoT[(size_t)n * CIN + k0 + g * 8];
            acc[nt] = __builtin_amdgcn_mfma_f32_16x16x32_bf16(af, wf, acc[nt], 0, 0, 0);
        }
    }

#pragma unroll
    for (int nt = 0; nt < NTW; ++nt)
#pragma unroll
        for (int r = 0; r < 4; ++r) {
            const size_t off = (size_t)(r0 + 4 * g + r) * COUT + (w * NTW + nt) * 16 + q16;
            if constexpr (BF16OUT) ((u16*)Hout)[off] = f2bf(acc[nt][r]);
            else                   ((float*)Hout)[off] = acc[nt][r];
        }
}

// ---------------------------------------------------------------------------
// Mean over N + 3-layer MLP. One block per batch element.
// ---------------------------------------------------------------------------
__global__ void pool_mlp(const float* __restrict__ H2,
                         const float* __restrict__ W1, const float* __restrict__ b1,
                         const float* __restrict__ W2, const float* __restrict__ b2,
                         const float* __restrict__ W3, const float* __restrict__ b3,
                         float* __restrict__ out) {
    const int b = blockIdx.x;
    const int tid = threadIdx.x;       // 256
    __shared__ float red[4][64];
    __shared__ float mean[64];
    __shared__ float h1[32];
    __shared__ float h2[16];

    const int o = tid & 63;
    const int g = tid >> 6;
    float acc = 0.f;
    for (int n = g; n < NN; n += 4) acc += H2[((size_t)b * NN + n) * 64 + o];
    red[g][o] = acc;
    __syncthreads();
    if (g == 0) mean[o] = (red[0][o] + red[1][o] + red[2][o] + red[3][o]) * (1.0f / 1024.0f);
    __syncthreads();

    if (tid < 32) {
        float a = b1[tid];
#pragma unroll
        for (int f = 0; f < 64; ++f) a = fmaf(mean[f], W1[f * 32 + tid], a);
        h1[tid] = fmaxf(a, 0.f);
    }
    __syncthreads();
    if (tid < 16) {
        float a = b2[tid];
#pragma unroll
        for (int f = 0; f < 32; ++f) a = fmaf(h1[f], W2[f * 16 + tid], a);
        h2[tid] = fmaxf(a, 0.f);
    }
    __syncthreads();
    if (tid == 0) {
        float a = b3[0];
#pragma unroll
        for (int f = 0; f < 16; ++f) a = fmaf(h2[f], W3[f], a);
        out[b] = a;
    }
}

// ---------------------------------------------------------------------------
extern "C" void kernel_launch(void* const* d_in, const int* in_sizes, int n_in,
                              void* d_out, int out_size, void* d_ws, size_t ws_size,
                              hipStream_t stream) {
    const float* X   = (const float*)d_in[0];
    const float* A   = (const float*)d_in[1];
    const float* Wq1 = (const float*)d_in[2];
    const float* Wk1 = (const float*)d_in[3];
    const float* Wv1 = (const float*)d_in[4];
    const float* Wo1 = (const float*)d_in[5];
    const float* Wq2 = (const float*)d_in[6];
    const float* Wk2 = (const float*)d_in[7];
    const float* Wv2 = (const float*)d_in[8];
    const float* Wo2 = (const float*)d_in[9];
    const float* W1  = (const float*)d_in[10];
    const float* b1  = (const float*)d_in[11];
    const float* W2  = (const float*)d_in[12];
    const float* b2  = (const float*)d_in[13];
    const float* W3  = (const float*)d_in[14];
    const float* b3  = (const float*)d_in[15];
    float* out = (float*)d_out;

    // workspace layout (u16 units unless noted)
    u32* bits   = (u32*)d_ws;                      // 1 MB
    u16* base   = (u16*)(bits + 262144);
    u16* Qb1    = base;  base += 8388608;
    u16* Kb1    = base;  base += 8388608;
    u16* VT1    = base;  base += 8388608;          // chunk-major V
    u16* ctx1b  = base;  base += 8388608;          // bf16 ctx [B,N,1024]
    u16* WoT1   = base;  base += 131072;           // [128][1024]
    u16* Qb2    = base;  base += 4194304;
    u16* Kb2    = base;  base += 4194304;
    u16* VT2    = base;  base += 4194304;
    u16* ctx2b  = base;  base += 4194304;          // bf16 ctx [B,N,512]
    u16* WoT2   = base;  base += 32768;            // [64][512]
    u16* Xb     = base;  base += 524288;           // bf16 X [8192][64]
    u16* WqkvT1 = base;  base += 196608;           // [3072][64]
    u16* WqkvT2 = base;  base += 196608;           // [1536][128]
    u16* H1b    = base;  base += 1048576;          // bf16 H1 [8192][128]
    float* H2   = (float*)base;                    // f32 [B,N,64]

    const int ROWS = NB * NN;                     // 8192
    const float LOG2E = 1.4426950408889634f;

    // prep (independent)
    mask_bits<<<ROWS, 256, 0, stream>>>(A, bits);
    cvt_bf16<<<ROWS * 64 / 8 / 256, 256, 0, stream>>>(X, Xb);
    cvt_qkvT<64, 1024><<<3072 * 64 / 8 / 256, 256, 0, stream>>>(Wq1, Wk1, Wv1, WqkvT1);
    cvt_qkvT<128, 512><<<1536 * 128 / 8 / 256, 256, 0, stream>>>(Wq2, Wk2, Wv2, WqkvT2);
    cvt_woT<1024, 128><<<128 * 1024 / 8 / 256, 256, 0, stream>>>(Wo1, WoT1);
    cvt_woT<512, 64><<<64 * 512 / 8 / 256, 256, 0, stream>>>(Wo2, WoT2);

    // ----- layer 1 (D = 128) -----
    proj_mfma<64, 1024, 128><<<ROWS / 16, 256, 0, stream>>>(
        Xb, WqkvT1, Qb1, Kb1, VT1, 0.08838834764831845f * LOG2E);
    attn_v9<128><<<1024, 256, 0, stream>>>(Qb1, Kb1, VT1, bits, ctx1b);
    wo_mfma<1024, 128, true><<<ROWS / 16, 256, 0, stream>>>(ctx1b, WoT1, H1b);

    // ----- layer 2 (D = 64) -----
    proj_mfma<128, 512, 64><<<ROWS / 16, 256, 0, stream>>>(
        H1b, WqkvT2, Qb2, Kb2, VT2, 0.125f * LOG2E);
    attn_v9<64><<<1024, 256, 0, stream>>>(Qb2, Kb2, VT2, bits, ctx2b);
    wo_mfma<512, 64, false><<<ROWS / 16, 256, 0, stream>>>(ctx2b, WoT2, H2);

    // ----- pool + MLP -----
    pool_mlp<<<NB, 256, 0, stream>>>(H2, W1, b1, W2, b2, W3, b3, out);
}

// Round 14
// 276.836 us; speedup vs baseline: 2.7218x; 1.0028x over previous
//
#include <hip/hip_runtime.h>
#include <hip/hip_bf16.h>
#include <math.h>

// B=8, N=1024, F=64, HEADS=8, u1=128, u2=64
#define NB 8
#define NN 1024
#define NH 8

typedef __attribute__((ext_vector_type(8))) short bf16x8;
typedef __attribute__((ext_vector_type(4))) float f32x4;
typedef unsigned int u32;
typedef unsigned short u16;

__device__ __forceinline__ u16 f2bf(float f) {
    union { float f; u32 u; } v; v.f = f;
    const u32 u = v.u;
    return (u16)((u + 0x7fffu + ((u >> 16) & 1u)) >> 16);
}

// packed f32x2 -> bf16x2 (RTNE), dst.lo = lo, dst.hi = hi
__device__ __forceinline__ u32 cvt_pk_bf16(float lo, float hi) {
    u32 r;
    asm("v_cvt_pk_bf16_f32 %0, %1, %2" : "=v"(r) : "v"(lo), "v"(hi));
    return r;
}

// ---------------------------------------------------------------------------
// Mask bit-pack: A [B,N,N] f32 (0/1) -> bits [B*N, 32] u32 (bit=1 => masked)
// ---------------------------------------------------------------------------
__global__ __launch_bounds__(256) void mask_bits(const float* __restrict__ A,
                                                 u32* __restrict__ bits) {
    const int row = blockIdx.x;            // 0..B*N-1
    const int tid = threadIdx.x;
    const int lane = tid & 63;
    const float* __restrict__ ar = A + (size_t)row * NN;
#pragma unroll
    for (int it = 0; it < 4; ++it) {
        const int i = it * 256 + tid;
        const unsigned long long bal = __ballot(ar[i] != 0.0f);
        const int w0 = (it * 256 + (tid & ~63)) >> 5;
        if (lane == 0)  bits[(size_t)row * 32 + w0]     = (u32)bal;
        if (lane == 32) bits[(size_t)row * 32 + w0 + 1] = (u32)(bal >> 32);
    }
}

// ---------------------------------------------------------------------------
// f32 -> bf16 vector convert (8 elems/thread).
// ---------------------------------------------------------------------------
__global__ __launch_bounds__(256)
void cvt_bf16(const float* __restrict__ in, u16* __restrict__ out) {
    const int i = blockIdx.x * 256 + threadIdx.x;
    const float4 a = ((const float4*)in)[2 * i];
    const float4 b = ((const float4*)in)[2 * i + 1];
    u16 t[8] = {f2bf(a.x), f2bf(a.y), f2bf(a.z), f2bf(a.w),
                f2bf(b.x), f2bf(b.y), f2bf(b.z), f2bf(b.w)};
    ((uint4*)out)[i] = *(uint4*)t;
}

// ---------------------------------------------------------------------------
// QKV weight transpose+bf16: WT[c][f] over c in [0,3*HD) = {Wq|Wk|Wv}[f][c%HD]
// ---------------------------------------------------------------------------
template <int KIN, int HD>
__global__ __launch_bounds__(256)
void cvt_qkvT(const float* __restrict__ Wq, const float* __restrict__ Wk,
              const float* __restrict__ Wv, u16* __restrict__ WT) {
    const int idx = blockIdx.x * 256 + threadIdx.x;   // c*(KIN/8) + f8
    const int c  = idx / (KIN / 8);
    const int f0 = (idx % (KIN / 8)) * 8;
    const float* __restrict__ W = (c < HD) ? Wq : (c < 2 * HD) ? Wk : Wv;
    const int cc = c % HD;
    u16 tmp[8];
#pragma unroll
    for (int j = 0; j < 8; ++j)
        tmp[j] = f2bf(W[(size_t)(f0 + j) * HD + cc]);
    *(uint4*)&WT[(size_t)c * KIN + f0] = *(uint4*)tmp;
}

// ---------------------------------------------------------------------------
// Wo transpose+bf16: WoT[n][k] = bf16(Wo[k][n]).
// ---------------------------------------------------------------------------
template <int CIN, int COUT>
__global__ __launch_bounds__(256)
void cvt_woT(const float* __restrict__ Wo, u16* __restrict__ WoT) {
    const int idx = blockIdx.x * 256 + threadIdx.x;   // n*CIN/8 + k8
    const int n  = idx / (CIN / 8);
    const int k0 = (idx % (CIN / 8)) * 8;
    u16 tmp[8];
#pragma unroll
    for (int j = 0; j < 8; ++j)
        tmp[j] = f2bf(Wo[(size_t)(k0 + j) * COUT + n]);
    *(uint4*)&WoT[(size_t)n * CIN + k0] = *(uint4*)tmp;
}

// ---------------------------------------------------------------------------
// MFMA QKV projection (R12-verified).  Xb: [rows][KIN] bf16.  WT: [3*HD][KIN].
// Outputs: Qb [bh][n][D] (x qscale), Kb same, VT chunk-major permuted
// [bh][ch][D][32''] with n'' = 8g + r + 4*grp for this 16-row tile.
// ---------------------------------------------------------------------------
template <int KIN, int HD, int D>
__global__ __launch_bounds__(256)
void proj_mfma(const u16* __restrict__ Xb,
               const u16* __restrict__ WT,
               u16* __restrict__ Qb,
               u16* __restrict__ Kb,
               u16* __restrict__ VT,
               const float qscale) {
    constexpr int NKT = KIN / 32;          // k-steps (2 / 4)
    constexpr int NTW = (3 * HD / 16) / 4; // n-tiles per wave (48 / 24)

    const int tid  = threadIdx.x;
    const int w    = tid >> 6;
    const int lane = tid & 63;
    const int g    = lane >> 4;
    const int q16  = lane & 15;
    const int r0   = blockIdx.x * 16;
    const int b    = r0 >> 10;
    const int n0   = r0 & 1023;
    const int ch   = n0 >> 5;
    const int grp  = (n0 >> 4) & 1;

    bf16x8 af[NKT];
#pragma unroll
    for (int t = 0; t < NKT; ++t)
        af[t] = *(const bf16x8*)&Xb[(size_t)(r0 + q16) * KIN + t * 32 + g * 8];

#pragma unroll 1
    for (int i = 0; i < NTW; ++i) {
        const int nt = w + 4 * i;
        const int c0 = nt * 16;
        f32x4 acc = (f32x4)0.f;
#pragma unroll
        for (int t = 0; t < NKT; ++t) {
            const bf16x8 wf = *(const bf16x8*)&WT[(size_t)(c0 + q16) * KIN + t * 32 + g * 8];
            acc = __builtin_amdgcn_mfma_f32_16x16x32_bf16(af[t], wf, acc, 0, 0, 0);
        }

        const int wcl = c0 / HD;           // 0=Q 1=K 2=V (wave-uniform)
        const int cc  = c0 % HD;
        const int h   = cc / D;
        const int d0  = cc % D;
        const int bh  = b * NH + h;

        if (wcl == 2) {
            u16 tmp[4];
#pragma unroll
            for (int r = 0; r < 4; ++r) tmp[r] = f2bf(acc[r]);
            *(uint2*)&VT[(((size_t)bh * 32 + ch) * D + d0 + q16) * 32
                         + 8 * g + 4 * grp] = *(uint2*)tmp;
        } else {
            u16* __restrict__ O = wcl ? Kb : Qb;
            const float sc = wcl ? 1.0f : qscale;
#pragma unroll
            for (int r = 0; r < 4; ++r)
                O[((size_t)bh * NN + n0 + 4 * g + r) * D + d0 + q16] = f2bf(acc[r] * sc);
        }
    }
}

// ---------------------------------------------------------------------------
// MFMA flash attention v10: v9's verified body with
//   - 32 q-rows per wave (2 q-subtiles sharing staged K/V and kf/vf reads)
//   - LDS DOUBLE-BUFFER -> ONE barrier per chunk
//   - loads issued 2 chunks ahead (write ch+1 to idle buf, then load ch+2)
//   - mask as cndmask-after-exp2 (bit-exact: exp2(s-1e9)=0 = select 0)
// Grid 512 blocks = 8 XCDs x 8 bh x 8 q-blocks; block = 4 waves x 32q = 128q.
// ---------------------------------------------------------------------------
template <int D>
__global__ __launch_bounds__(256, 2)
void attn_v10(const u16* __restrict__ Qb,
              const u16* __restrict__ Kb,
              const u16* __restrict__ VT,
              const u32* __restrict__ bits,
              u16* __restrict__ Ob) {
    constexpr int ND4 = D / 32;            // QK k-steps per kb (4 / 2)
    constexpr int NDT = D / 16;            // PV d-tiles (8 / 4)
    constexpr int KROWB = 2 * D;           // K LDS row bytes (256 / 128)
    constexpr int KBYTES = 32 * KROWB;     // 8KB / 4KB
    constexpr int VBYTES = D * 80;         // 10KB / 5KB

    const int tid  = threadIdx.x;
    const int w    = tid >> 6;
    const int lane = tid & 63;
    const int g    = lane >> 4;            // 0..3
    const int q16  = lane & 15;

    // 512 blocks -> 8 XCDs x 8 bh x 8 q-blocks (bijective; bid%8 = XCD)
    const int xcd    = blockIdx.x & 7;
    const int within = blockIdx.x >> 3;    // 0..63
    const int bh     = xcd * 8 + (within >> 3);
    const int b      = bh >> 3, h = bh & 7;
    const int q0     = ((within & 7) * 4 + w) * 32;   // 32 q-rows per wave

    const u16* __restrict__ qbase = Qb + (size_t)bh * NN * D;
    const u16* __restrict__ kbase = Kb + (size_t)bh * NN * D;
    const u16* __restrict__ vbase = VT + (size_t)bh * 32 * D * 32;  // chunk-major
    const u32* __restrict__ brow0 = bits + ((size_t)b * NN + q0 + q16) * 32;
    const u32* __restrict__ brow1 = brow0 + 16 * 32;

    __shared__ alignas(16) char KsB[2][KBYTES];
    __shared__ alignas(16) char VsB[2][VBYTES];

    bool doK, doV;
    int kRow = 0, kA = 0, vD = 0, vHalf = 0;
    if constexpr (D == 128) {
        doK = true; doV = true;
        kRow = tid >> 3; kA = tid & 7;
        vD = tid >> 1;  vHalf = tid & 1;
    } else {
        doK = (tid < 128); doV = !doK;
        kRow = tid >> 2; kA = tid & 3;
        const int vt = tid - 128;
        vD = vt >> 1;   vHalf = vt & 1;
    }

    // Q as B-fragment: col=q16=q, k = f*32 + g*8 + j; 2 q-subtiles
    bf16x8 qf[2][ND4];
#pragma unroll
    for (int qs = 0; qs < 2; ++qs)
#pragma unroll
        for (int f = 0; f < ND4; ++f)
            qf[qs][f] = *(const bf16x8*)
                &qbase[(size_t)(q0 + qs * 16 + q16) * D + f * 32 + g * 8];

    f32x4 acc[2][NDT];
#pragma unroll
    for (int qs = 0; qs < 2; ++qs)
#pragma unroll
        for (int dt = 0; dt < NDT; ++dt) acc[qs][dt] = (f32x4)0.f;
    float l0 = 0.f, l1 = 0.f;

    uint4 sk0, sk1, sv0, sv1;
    auto stage_load = [&](int ch) {
        if (doK) {
            const u16* src = kbase + (size_t)(ch * 32 + kRow) * D + kA * 16;
            sk0 = *(const uint4*)(src);
            sk1 = *(const uint4*)(src + 8);
        }
        if (doV) {
            const u16* src = vbase + ((size_t)ch * D + vD) * 32 + vHalf * 16;
            sv0 = *(const uint4*)(src);
            sv1 = *(const uint4*)(src + 8);
        }
    };
    auto stage_write = [&](int buf) {
        if (doK) {
            char* kr = KsB[buf] + kRow * KROWB;
            *(uint4*)(kr + (((2 * kA)     ^ (kRow & 7)) * 16)) = sk0;
            *(uint4*)(kr + (((2 * kA + 1) ^ (kRow & 7)) * 16)) = sk1;
        }
        if (doV) {
            char* vr = VsB[buf] + vD * 80 + vHalf * 32;
            *(uint4*)(vr)      = sv0;
            *(uint4*)(vr + 16) = sv1;
        }
    };

    // prologue: buf0 = chunk 0; chunk 1 in regs
    stage_load(0);
    stage_write(0);
    stage_load(1);
    __syncthreads();

#pragma unroll 1
    for (int ch = 0; ch < 32; ++ch) {
        const int cur = ch & 1;
        // write chunk ch+1 into the idle buffer, then issue loads for ch+2
        if (ch + 1 < 32) stage_write(cur ^ 1);
        if (ch + 2 < 32) stage_load(ch + 2);

        const u32 bw0 = brow0[ch];
        const u32 bw1 = brow1[ch];

        // K A-fragments from swizzled LDS (shared by both q-subtiles)
        bf16x8 kf[2][ND4];
#pragma unroll
        for (int kb = 0; kb < 2; ++kb)
#pragma unroll
            for (int f = 0; f < ND4; ++f)
                kf[kb][f] = *(const bf16x8*)
                    (KsB[cur] + (kb * 16 + q16) * KROWB + (((f * 4 + g) ^ (q16 & 7)) * 16));

        // QK^T: four independent MFMA chains (2 kb x 2 qs)
        f32x4 sA0 = (f32x4)0.f, sA1 = (f32x4)0.f;   // qs0: kb0, kb1
        f32x4 sB0 = (f32x4)0.f, sB1 = (f32x4)0.f;   // qs1
#pragma unroll
        for (int f = 0; f < ND4; ++f) {
            sA0 = __builtin_amdgcn_mfma_f32_16x16x32_bf16(kf[0][f], qf[0][f], sA0, 0, 0, 0);
            sA1 = __builtin_amdgcn_mfma_f32_16x16x32_bf16(kf[1][f], qf[0][f], sA1, 0, 0, 0);
            sB0 = __builtin_amdgcn_mfma_f32_16x16x32_bf16(kf[0][f], qf[1][f], sB0, 0, 0, 0);
            sB1 = __builtin_amdgcn_mfma_f32_16x16x32_bf16(kf[1][f], qf[1][f], sB1, 0, 0, 0);
        }

        // V B-fragments (shared by both q-subtiles)
        bf16x8 vf[NDT];
#pragma unroll
        for (int dt = 0; dt < NDT; ++dt)
            vf[dt] = *(const bf16x8*)(VsB[cur] + (dt * 16 + q16) * 80 + g * 16);

        // softmax (no max tracking); reg r of s[kb] is key 16kb+4g+r
        const u32 sh0 = bw0 >> (g * 4);
        const u32 sh1 = bw1 >> (g * 4);
        float pA0[4], pA1[4], pB0[4], pB1[4];
#pragma unroll
        for (int r = 0; r < 4; ++r) {
            const float eA0 = exp2f(sA0[r]), eA1 = exp2f(sA1[r]);
            const float eB0 = exp2f(sB0[r]), eB1 = exp2f(sB1[r]);
            pA0[r] = ((sh0 >> r) & 1u)        ? 0.f : eA0;
            pA1[r] = ((sh0 >> (16 + r)) & 1u) ? 0.f : eA1;
            pB0[r] = ((sh1 >> r) & 1u)        ? 0.f : eB0;
            pB1[r] = ((sh1 >> (16 + r)) & 1u) ? 0.f : eB1;
        }
        l0 += ((pA0[0] + pA0[1]) + (pA0[2] + pA0[3]))
            + ((pA1[0] + pA1[1]) + (pA1[2] + pA1[3]));
        l1 += ((pB0[0] + pB0[1]) + (pB0[2] + pB0[3]))
            + ((pB1[0] + pB1[1]) + (pB1[2] + pB1[3]));

        union { u32 u[4]; bf16x8 v; } paA, paB;
        paA.u[0] = cvt_pk_bf16(pA0[0], pA0[1]);
        paA.u[1] = cvt_pk_bf16(pA0[2], pA0[3]);
        paA.u[2] = cvt_pk_bf16(pA1[0], pA1[1]);
        paA.u[3] = cvt_pk_bf16(pA1[2], pA1[3]);
        paB.u[0] = cvt_pk_bf16(pB0[0], pB0[1]);
        paB.u[1] = cvt_pk_bf16(pB0[2], pB0[3]);
        paB.u[2] = cvt_pk_bf16(pB1[0], pB1[1]);
        paB.u[3] = cvt_pk_bf16(pB1[2], pB1[3]);

        // PV: one K=32 A-frag per q-subtile
#pragma unroll
        for (int dt = 0; dt < NDT; ++dt) {
            acc[0][dt] = __builtin_amdgcn_mfma_f32_16x16x32_bf16(paA.v, vf[dt], acc[0][dt], 0, 0, 0);
            acc[1][dt] = __builtin_amdgcn_mfma_f32_16x16x32_bf16(paB.v, vf[dt], acc[1][dt], 0, 0, 0);
        }

        __syncthreads();                   // buf[cur^1] writes visible; reads of buf[cur] done
    }

    // epilogue per q-subtile
#pragma unroll
    for (int qs = 0; qs < 2; ++qs) {
        float l = qs ? l1 : l0;
        l += __shfl_xor(l, 16);
        l += __shfl_xor(l, 32);
        const float inv = 1.0f / l;
        float ivr[4];
#pragma unroll
        for (int r = 0; r < 4; ++r) ivr[r] = __shfl(inv, g * 4 + r);
#pragma unroll
        for (int dt = 0; dt < NDT; ++dt)
#pragma unroll
            for (int r = 0; r < 4; ++r) {
                const int q = q0 + qs * 16 + g * 4 + r;
                Ob[(((size_t)b * NN + q) * NH + h) * D + dt * 16 + q16] =
                    f2bf(acc[qs][dt][r] * ivr[r]);
            }
    }
}

// ---------------------------------------------------------------------------
// Output projection via MFMA (R11/R12-verified).
// ---------------------------------------------------------------------------
template <int CIN, int COUT, bool BF16OUT>
__global__ __launch_bounds__(256)
void wo_mfma(const u16* __restrict__ ctxb,
             const u16* __restrict__ WoT,
             void* __restrict__ Hout) {
    constexpr int NTW = COUT / 64;         // n-tiles per wave (2 / 1)
    const int tid  = threadIdx.x;
    const int w    = tid >> 6;
    const int lane = tid & 63;
    const int g    = lane >> 4;
    const int q16  = lane & 15;
    const int r0   = blockIdx.x * 16;

    f32x4 acc[NTW];
#pragma unroll
    for (int nt = 0; nt < NTW; ++nt) acc[nt] = (f32x4)0.f;

    const u16* __restrict__ arow = ctxb + (size_t)(r0 + q16) * CIN + g * 8;

#pragma unroll 4
    for (int k0 = 0; k0 < CIN; k0 += 32) {
        const bf16x8 af = *(const bf16x8*)(arow + k0);
#pragma unroll
        for (int nt = 0; nt < NTW; ++nt) {
            const int n = (w * NTW + nt) * 16 + q16;
            const bf16x8 wf = *(const bf16x8*)&WoT[(size_t)n * CIN + k0 + g * 8];
            acc[nt] = __builtin_amdgcn_mfma_f32_16x16x32_bf16(af, wf, acc[nt], 0, 0, 0);
        }
    }

#pragma unroll
    for (int nt = 0; nt < NTW; ++nt)
#pragma unroll
        for (int r = 0; r < 4; ++r) {
            const size_t off = (size_t)(r0 + 4 * g + r) * COUT + (w * NTW + nt) * 16 + q16;
            if constexpr (BF16OUT) ((u16*)Hout)[off] = f2bf(acc[nt][r]);
            else                   ((float*)Hout)[off] = acc[nt][r];
        }
}

// ---------------------------------------------------------------------------
// Mean over N + 3-layer MLP. One block per batch element.
// ---------------------------------------------------------------------------
__global__ void pool_mlp(const float* __restrict__ H2,
                         const float* __restrict__ W1, const float* __restrict__ b1,
                         const float* __restrict__ W2, const float* __restrict__ b2,
                         const float* __restrict__ W3, const float* __restrict__ b3,
                         float* __restrict__ out) {
    const int b = blockIdx.x;
    const int tid = threadIdx.x;       // 256
    __shared__ float red[4][64];
    __shared__ float mean[64];
    __shared__ float h1[32];
    __shared__ float h2[16];

    const int o = tid & 63;
    const int g = tid >> 6;
    float acc = 0.f;
    for (int n = g; n < NN; n += 4) acc += H2[((size_t)b * NN + n) * 64 + o];
    red[g][o] = acc;
    __syncthreads();
    if (g == 0) mean[o] = (red[0][o] + red[1][o] + red[2][o] + red[3][o]) * (1.0f / 1024.0f);
    __syncthreads();

    if (tid < 32) {
        float a = b1[tid];
#pragma unroll
        for (int f = 0; f < 64; ++f) a = fmaf(mean[f], W1[f * 32 + tid], a);
        h1[tid] = fmaxf(a, 0.f);
    }
    __syncthreads();
    if (tid < 16) {
        float a = b2[tid];
#pragma unroll
        for (int f = 0; f < 32; ++f) a = fmaf(h1[f], W2[f * 16 + tid], a);
        h2[tid] = fmaxf(a, 0.f);
    }
    __syncthreads();
    if (tid == 0) {
        float a = b3[0];
#pragma unroll
        for (int f = 0; f < 16; ++f) a = fmaf(h2[f], W3[f], a);
        out[b] = a;
    }
}

// ---------------------------------------------------------------------------
extern "C" void kernel_launch(void* const* d_in, const int* in_sizes, int n_in,
                              void* d_out, int out_size, void* d_ws, size_t ws_size,
                              hipStream_t stream) {
    const float* X   = (const float*)d_in[0];
    const float* A   = (const float*)d_in[1];
    const float* Wq1 = (const float*)d_in[2];
    const float* Wk1 = (const float*)d_in[3];
    const float* Wv1 = (const float*)d_in[4];
    const float* Wo1 = (const float*)d_in[5];
    const float* Wq2 = (const float*)d_in[6];
    const float* Wk2 = (const float*)d_in[7];
    const float* Wv2 = (const float*)d_in[8];
    const float* Wo2 = (const float*)d_in[9];
    const float* W1  = (const float*)d_in[10];
    const float* b1  = (const float*)d_in[11];
    const float* W2  = (const float*)d_in[12];
    const float* b2  = (const float*)d_in[13];
    const float* W3  = (const float*)d_in[14];
    const float* b3  = (const float*)d_in[15];
    float* out = (float*)d_out;

    // workspace layout (u16 units unless noted)
    u32* bits   = (u32*)d_ws;                      // 1 MB
    u16* base   = (u16*)(bits + 262144);
    u16* Qb1    = base;  base += 8388608;
    u16* Kb1    = base;  base += 8388608;
    u16* VT1    = base;  base += 8388608;          // chunk-major V
    u16* ctx1b  = base;  base += 8388608;          // bf16 ctx [B,N,1024]
    u16* WoT1   = base;  base += 131072;           // [128][1024]
    u16* Qb2    = base;  base += 4194304;
    u16* Kb2    = base;  base += 4194304;
    u16* VT2    = base;  base += 4194304;
    u16* ctx2b  = base;  base += 4194304;          // bf16 ctx [B,N,512]
    u16* WoT2   = base;  base += 32768;            // [64][512]
    u16* Xb     = base;  base += 524288;           // bf16 X [8192][64]
    u16* WqkvT1 = base;  base += 196608;           // [3072][64]
    u16* WqkvT2 = base;  base += 196608;           // [1536][128]
    u16* H1b    = base;  base += 1048576;          // bf16 H1 [8192][128]
    float* H2   = (float*)base;                    // f32 [B,N,64]

    const int ROWS = NB * NN;                     // 8192
    const float LOG2E = 1.4426950408889634f;

    // prep (independent)
    mask_bits<<<ROWS, 256, 0, stream>>>(A, bits);
    cvt_bf16<<<ROWS * 64 / 8 / 256, 256, 0, stream>>>(X, Xb);
    cvt_qkvT<64, 1024><<<3072 * 64 / 8 / 256, 256, 0, stream>>>(Wq1, Wk1, Wv1, WqkvT1);
    cvt_qkvT<128, 512><<<1536 * 128 / 8 / 256, 256, 0, stream>>>(Wq2, Wk2, Wv2, WqkvT2);
    cvt_woT<1024, 128><<<128 * 1024 / 8 / 256, 256, 0, stream>>>(Wo1, WoT1);
    cvt_woT<512, 64><<<64 * 512 / 8 / 256, 256, 0, stream>>>(Wo2, WoT2);

    // ----- layer 1 (D = 128) -----
    proj_mfma<64, 1024, 128><<<ROWS / 16, 256, 0, stream>>>(
        Xb, WqkvT1, Qb1, Kb1, VT1, 0.08838834764831845f * LOG2E);
    attn_v10<128><<<512, 256, 0, stream>>>(Qb1, Kb1, VT1, bits, ctx1b);
    wo_mfma<1024, 128, true><<<ROWS / 16, 256, 0, stream>>>(ctx1b, WoT1, H1b);

    // ----- layer 2 (D = 64) -----
    proj_mfma<128, 512, 64><<<ROWS / 16, 256, 0, stream>>>(
        H1b, WqkvT2, Qb2, Kb2, VT2, 0.125f * LOG2E);
    attn_v10<64><<<512, 256, 0, stream>>>(Qb2, Kb2, VT2, bits, ctx2b);
    wo_mfma<512, 64, false><<<ROWS / 16, 256, 0, stream>>>(ctx2b, WoT2, H2);

    // ----- pool + MLP -----
    pool_mlp<<<NB, 256, 0, stream>>>(H2, W1, b1, W2, b2, W3, b3, out);
}

// Round 15
// 218.771 us; speedup vs baseline: 3.4442x; 1.2654x over previous
//
#include <hip/hip_runtime.h>
#include <hip/hip_bf16.h>
#include <math.h>

// B=8, N=1024, F=64, HEADS=8, u1=128, u2=64
#define NB 8
#define NN 1024
#define NH 8

typedef __attribute__((ext_vector_type(8))) short bf16x8;
typedef __attribute__((ext_vector_type(4))) float f32x4;
typedef unsigned int u32;
typedef unsigned short u16;

__device__ __forceinline__ u16 f2bf(float f) {
    union { float f; u32 u; } v; v.f = f;
    const u32 u = v.u;
    return (u16)((u + 0x7fffu + ((u >> 16) & 1u)) >> 16);
}

// packed f32x2 -> bf16x2 (RTNE), dst.lo = lo, dst.hi = hi
__device__ __forceinline__ u32 cvt_pk_bf16(float lo, float hi) {
    u32 r;
    asm("v_cvt_pk_bf16_f32 %0, %1, %2" : "=v"(r) : "v"(lo), "v"(hi));
    return r;
}

// ---------------------------------------------------------------------------
// Mask bit-pack: A [B,N,N] f32 (0/1) -> bits [B*N, 32] u32 (bit=1 => masked)
// ---------------------------------------------------------------------------
__global__ __launch_bounds__(256) void mask_bits(const float* __restrict__ A,
                                                 u32* __restrict__ bits) {
    const int row = blockIdx.x;            // 0..B*N-1
    const int tid = threadIdx.x;
    const int lane = tid & 63;
    const float* __restrict__ ar = A + (size_t)row * NN;
#pragma unroll
    for (int it = 0; it < 4; ++it) {
        const int i = it * 256 + tid;
        const unsigned long long bal = __ballot(ar[i] != 0.0f);
        const int w0 = (it * 256 + (tid & ~63)) >> 5;
        if (lane == 0)  bits[(size_t)row * 32 + w0]     = (u32)bal;
        if (lane == 32) bits[(size_t)row * 32 + w0 + 1] = (u32)(bal >> 32);
    }
}

// ---------------------------------------------------------------------------
// f32 -> bf16 vector convert (8 elems/thread).
// ---------------------------------------------------------------------------
__global__ __launch_bounds__(256)
void cvt_bf16(const float* __restrict__ in, u16* __restrict__ out) {
    const int i = blockIdx.x * 256 + threadIdx.x;
    const float4 a = ((const float4*)in)[2 * i];
    const float4 b = ((const float4*)in)[2 * i + 1];
    u16 t[8] = {f2bf(a.x), f2bf(a.y), f2bf(a.z), f2bf(a.w),
                f2bf(b.x), f2bf(b.y), f2bf(b.z), f2bf(b.w)};
    ((uint4*)out)[i] = *(uint4*)t;
}

// ---------------------------------------------------------------------------
// QKV weight transpose+bf16: WT[c][f] over c in [0,3*HD) = {Wq|Wk|Wv}[f][c%HD]
// ---------------------------------------------------------------------------
template <int KIN, int HD>
__global__ __launch_bounds__(256)
void cvt_qkvT(const float* __restrict__ Wq, const float* __restrict__ Wk,
              const float* __restrict__ Wv, u16* __restrict__ WT) {
    const int idx = blockIdx.x * 256 + threadIdx.x;   // c*(KIN/8) + f8
    const int c  = idx / (KIN / 8);
    const int f0 = (idx % (KIN / 8)) * 8;
    const float* __restrict__ W = (c < HD) ? Wq : (c < 2 * HD) ? Wk : Wv;
    const int cc = c % HD;
    u16 tmp[8];
#pragma unroll
    for (int j = 0; j < 8; ++j)
        tmp[j] = f2bf(W[(size_t)(f0 + j) * HD + cc]);
    *(uint4*)&WT[(size_t)c * KIN + f0] = *(uint4*)tmp;
}

// ---------------------------------------------------------------------------
// Wo transpose+bf16: WoT[n][k] = bf16(Wo[k][n]).
// ---------------------------------------------------------------------------
template <int CIN, int COUT>
__global__ __launch_bounds__(256)
void cvt_woT(const float* __restrict__ Wo, u16* __restrict__ WoT) {
    const int idx = blockIdx.x * 256 + threadIdx.x;   // n*CIN/8 + k8
    const int n  = idx / (CIN / 8);
    const int k0 = (idx % (CIN / 8)) * 8;
    u16 tmp[8];
#pragma unroll
    for (int j = 0; j < 8; ++j)
        tmp[j] = f2bf(Wo[(size_t)(k0 + j) * COUT + n]);
    *(uint4*)&WoT[(size_t)n * CIN + k0] = *(uint4*)tmp;
}

// ---------------------------------------------------------------------------
// MFMA QKV projection (R12-verified).  Xb: [rows][KIN] bf16.  WT: [3*HD][KIN].
// Outputs: Qb [bh][n][D] (x qscale), Kb same, VT chunk-major permuted
// [bh][ch][D][32''] with n'' = 8g + r + 4*grp for this 16-row tile.
// ---------------------------------------------------------------------------
template <int KIN, int HD, int D>
__global__ __launch_bounds__(256)
void proj_mfma(const u16* __restrict__ Xb,
               const u16* __restrict__ WT,
               u16* __restrict__ Qb,
               u16* __restrict__ Kb,
               u16* __restrict__ VT,
               const float qscale) {
    constexpr int NKT = KIN / 32;          // k-steps (2 / 4)
    constexpr int NTW = (3 * HD / 16) / 4; // n-tiles per wave (48 / 24)

    const int tid  = threadIdx.x;
    const int w    = tid >> 6;
    const int lane = tid & 63;
    const int g    = lane >> 4;
    const int q16  = lane & 15;
    const int r0   = blockIdx.x * 16;
    const int b    = r0 >> 10;
    const int n0   = r0 & 1023;
    const int ch   = n0 >> 5;
    const int grp  = (n0 >> 4) & 1;

    bf16x8 af[NKT];
#pragma unroll
    for (int t = 0; t < NKT; ++t)
        af[t] = *(const bf16x8*)&Xb[(size_t)(r0 + q16) * KIN + t * 32 + g * 8];

#pragma unroll 1
    for (int i = 0; i < NTW; ++i) {
        const int nt = w + 4 * i;
        const int c0 = nt * 16;
        f32x4 acc = (f32x4)0.f;
#pragma unroll
        for (int t = 0; t < NKT; ++t) {
            const bf16x8 wf = *(const bf16x8*)&WT[(size_t)(c0 + q16) * KIN + t * 32 + g * 8];
            acc = __builtin_amdgcn_mfma_f32_16x16x32_bf16(af[t], wf, acc, 0, 0, 0);
        }

        const int wcl = c0 / HD;           // 0=Q 1=K 2=V (wave-uniform)
        const int cc  = c0 % HD;
        const int h   = cc / D;
        const int d0  = cc % D;
        const int bh  = b * NH + h;

        if (wcl == 2) {
            u16 tmp[4];
#pragma unroll
            for (int r = 0; r < 4; ++r) tmp[r] = f2bf(acc[r]);
            *(uint2*)&VT[(((size_t)bh * 32 + ch) * D + d0 + q16) * 32
                         + 8 * g + 4 * grp] = *(uint2*)tmp;
        } else {
            u16* __restrict__ O = wcl ? Kb : Qb;
            const float sc = wcl ? 1.0f : qscale;
#pragma unroll
            for (int r = 0; r < 4; ++r)
                O[((size_t)bh * NN + n0 + 4 * g + r) * D + d0 + q16] = f2bf(acc[r] * sc);
        }
    }
}

// ---------------------------------------------------------------------------
// MFMA flash attention v10 (R14): 32 q-rows/wave, LDS double-buffer, one
// barrier per chunk, loads 2 chunks ahead, mask-as-select. Verified.
// ---------------------------------------------------------------------------
template <int D>
__global__ __launch_bounds__(256, 2)
void attn_v10(const u16* __restrict__ Qb,
              const u16* __restrict__ Kb,
              const u16* __restrict__ VT,
              const u32* __restrict__ bits,
              u16* __restrict__ Ob) {
    constexpr int ND4 = D / 32;            // QK k-steps per kb (4 / 2)
    constexpr int NDT = D / 16;            // PV d-tiles (8 / 4)
    constexpr int KROWB = 2 * D;           // K LDS row bytes (256 / 128)
    constexpr int KBYTES = 32 * KROWB;     // 8KB / 4KB
    constexpr int VBYTES = D * 80;         // 10KB / 5KB

    const int tid  = threadIdx.x;
    const int w    = tid >> 6;
    const int lane = tid & 63;
    const int g    = lane >> 4;            // 0..3
    const int q16  = lane & 15;

    // 512 blocks -> 8 XCDs x 8 bh x 8 q-blocks (bijective; bid%8 = XCD)
    const int xcd    = blockIdx.x & 7;
    const int within = blockIdx.x >> 3;    // 0..63
    const int bh     = xcd * 8 + (within >> 3);
    const int b      = bh >> 3, h = bh & 7;
    const int q0     = ((within & 7) * 4 + w) * 32;   // 32 q-rows per wave

    const u16* __restrict__ qbase = Qb + (size_t)bh * NN * D;
    const u16* __restrict__ kbase = Kb + (size_t)bh * NN * D;
    const u16* __restrict__ vbase = VT + (size_t)bh * 32 * D * 32;  // chunk-major
    const u32* __restrict__ brow0 = bits + ((size_t)b * NN + q0 + q16) * 32;
    const u32* __restrict__ brow1 = brow0 + 16 * 32;

    __shared__ alignas(16) char KsB[2][KBYTES];
    __shared__ alignas(16) char VsB[2][VBYTES];

    bool doK, doV;
    int kRow = 0, kA = 0, vD = 0, vHalf = 0;
    if constexpr (D == 128) {
        doK = true; doV = true;
        kRow = tid >> 3; kA = tid & 7;
        vD = tid >> 1;  vHalf = tid & 1;
    } else {
        doK = (tid < 128); doV = !doK;
        kRow = tid >> 2; kA = tid & 3;
        const int vt = tid - 128;
        vD = vt >> 1;   vHalf = vt & 1;
    }

    // Q as B-fragment: col=q16=q, k = f*32 + g*8 + j; 2 q-subtiles
    bf16x8 qf[2][ND4];
#pragma unroll
    for (int qs = 0; qs < 2; ++qs)
#pragma unroll
        for (int f = 0; f < ND4; ++f)
            qf[qs][f] = *(const bf16x8*)
                &qbase[(size_t)(q0 + qs * 16 + q16) * D + f * 32 + g * 8];

    f32x4 acc[2][NDT];
#pragma unroll
    for (int qs = 0; qs < 2; ++qs)
#pragma unroll
        for (int dt = 0; dt < NDT; ++dt) acc[qs][dt] = (f32x4)0.f;
    float l0 = 0.f, l1 = 0.f;

    uint4 sk0, sk1, sv0, sv1;
    auto stage_load = [&](int ch) {
        if (doK) {
            const u16* src = kbase + (size_t)(ch * 32 + kRow) * D + kA * 16;
            sk0 = *(const uint4*)(src);
            sk1 = *(const uint4*)(src + 8);
        }
        if (doV) {
            const u16* src = vbase + ((size_t)ch * D + vD) * 32 + vHalf * 16;
            sv0 = *(const uint4*)(src);
            sv1 = *(const uint4*)(src + 8);
        }
    };
    auto stage_write = [&](int buf) {
        if (doK) {
            char* kr = KsB[buf] + kRow * KROWB;
            *(uint4*)(kr + (((2 * kA)     ^ (kRow & 7)) * 16)) = sk0;
            *(uint4*)(kr + (((2 * kA + 1) ^ (kRow & 7)) * 16)) = sk1;
        }
        if (doV) {
            char* vr = VsB[buf] + vD * 80 + vHalf * 32;
            *(uint4*)(vr)      = sv0;
            *(uint4*)(vr + 16) = sv1;
        }
    };

    // prologue: buf0 = chunk 0; chunk 1 in regs
    stage_load(0);
    stage_write(0);
    stage_load(1);
    __syncthreads();

#pragma unroll 1
    for (int ch = 0; ch < 32; ++ch) {
        const int cur = ch & 1;
        if (ch + 1 < 32) stage_write(cur ^ 1);
        if (ch + 2 < 32) stage_load(ch + 2);

        const u32 bw0 = brow0[ch];
        const u32 bw1 = brow1[ch];

        bf16x8 kf[2][ND4];
#pragma unroll
        for (int kb = 0; kb < 2; ++kb)
#pragma unroll
            for (int f = 0; f < ND4; ++f)
                kf[kb][f] = *(const bf16x8*)
                    (KsB[cur] + (kb * 16 + q16) * KROWB + (((f * 4 + g) ^ (q16 & 7)) * 16));

        f32x4 sA0 = (f32x4)0.f, sA1 = (f32x4)0.f;
        f32x4 sB0 = (f32x4)0.f, sB1 = (f32x4)0.f;
#pragma unroll
        for (int f = 0; f < ND4; ++f) {
            sA0 = __builtin_amdgcn_mfma_f32_16x16x32_bf16(kf[0][f], qf[0][f], sA0, 0, 0, 0);
            sA1 = __builtin_amdgcn_mfma_f32_16x16x32_bf16(kf[1][f], qf[0][f], sA1, 0, 0, 0);
            sB0 = __builtin_amdgcn_mfma_f32_16x16x32_bf16(kf[0][f], qf[1][f], sB0, 0, 0, 0);
            sB1 = __builtin_amdgcn_mfma_f32_16x16x32_bf16(kf[1][f], qf[1][f], sB1, 0, 0, 0);
        }

        bf16x8 vf[NDT];
#pragma unroll
        for (int dt = 0; dt < NDT; ++dt)
            vf[dt] = *(const bf16x8*)(VsB[cur] + (dt * 16 + q16) * 80 + g * 16);

        const u32 sh0 = bw0 >> (g * 4);
        const u32 sh1 = bw1 >> (g * 4);
        float pA0[4], pA1[4], pB0[4], pB1[4];
#pragma unroll
        for (int r = 0; r < 4; ++r) {
            const float eA0 = exp2f(sA0[r]), eA1 = exp2f(sA1[r]);
            const float eB0 = exp2f(sB0[r]), eB1 = exp2f(sB1[r]);
            pA0[r] = ((sh0 >> r) & 1u)        ? 0.f : eA0;
            pA1[r] = ((sh0 >> (16 + r)) & 1u) ? 0.f : eA1;
            pB0[r] = ((sh1 >> r) & 1u)        ? 0.f : eB0;
            pB1[r] = ((sh1 >> (16 + r)) & 1u) ? 0.f : eB1;
        }
        l0 += ((pA0[0] + pA0[1]) + (pA0[2] + pA0[3]))
            + ((pA1[0] + pA1[1]) + (pA1[2] + pA1[3]));
        l1 += ((pB0[0] + pB0[1]) + (pB0[2] + pB0[3]))
            + ((pB1[0] + pB1[1]) + (pB1[2] + pB1[3]));

        union { u32 u[4]; bf16x8 v; } paA, paB;
        paA.u[0] = cvt_pk_bf16(pA0[0], pA0[1]);
        paA.u[1] = cvt_pk_bf16(pA0[2], pA0[3]);
        paA.u[2] = cvt_pk_bf16(pA1[0], pA1[1]);
        paA.u[3] = cvt_pk_bf16(pA1[2], pA1[3]);
        paB.u[0] = cvt_pk_bf16(pB0[0], pB0[1]);
        paB.u[1] = cvt_pk_bf16(pB0[2], pB0[3]);
        paB.u[2] = cvt_pk_bf16(pB1[0], pB1[1]);
        paB.u[3] = cvt_pk_bf16(pB1[2], pB1[3]);

#pragma unroll
        for (int dt = 0; dt < NDT; ++dt) {
            acc[0][dt] = __builtin_amdgcn_mfma_f32_16x16x32_bf16(paA.v, vf[dt], acc[0][dt], 0, 0, 0);
            acc[1][dt] = __builtin_amdgcn_mfma_f32_16x16x32_bf16(paB.v, vf[dt], acc[1][dt], 0, 0, 0);
        }

        __syncthreads();
    }

    // epilogue per q-subtile
#pragma unroll
    for (int qs = 0; qs < 2; ++qs) {
        float l = qs ? l1 : l0;
        l += __shfl_xor(l, 16);
        l += __shfl_xor(l, 32);
        const float inv = 1.0f / l;
        float ivr[4];
#pragma unroll
        for (int r = 0; r < 4; ++r) ivr[r] = __shfl(inv, g * 4 + r);
#pragma unroll
        for (int dt = 0; dt < NDT; ++dt)
#pragma unroll
            for (int r = 0; r < 4; ++r) {
                const int q = q0 + qs * 16 + g * 4 + r;
                Ob[(((size_t)b * NN + q) * NH + h) * D + dt * 16 + q16] =
                    f2bf(acc[qs][dt][r] * ivr[r]);
            }
    }
}

// ---------------------------------------------------------------------------
// Output projection via MFMA (R11/R12-verified).
// ---------------------------------------------------------------------------
template <int CIN, int COUT, bool BF16OUT>
__global__ __launch_bounds__(256)
void wo_mfma(const u16* __restrict__ ctxb,
             const u16* __restrict__ WoT,
             void* __restrict__ Hout) {
    constexpr int NTW = COUT / 64;         // n-tiles per wave (2 / 1)
    const int tid  = threadIdx.x;
    const int w    = tid >> 6;
    const int lane = tid & 63;
    const int g    = lane >> 4;
    const int q16  = lane & 15;
    const int r0   = blockIdx.x * 16;

    f32x4 acc[NTW];
#pragma unroll
    for (int nt = 0; nt < NTW; ++nt) acc[nt] = (f32x4)0.f;

    const u16* __restrict__ arow = ctxb + (size_t)(r0 + q16) * CIN + g * 8;

#pragma unroll 4
    for (int k0 = 0; k0 < CIN; k0 += 32) {
        const bf16x8 af = *(const bf16x8*)(arow + k0);
#pragma unroll
        for (int nt = 0; nt < NTW; ++nt) {
            const int n = (w * NTW + nt) * 16 + q16;
            const bf16x8 wf = *(const bf16x8*)&WoT[(size_t)n * CIN + k0 + g * 8];
            acc[nt] = __builtin_amdgcn_mfma_f32_16x16x32_bf16(af, wf, acc[nt], 0, 0, 0);
        }
    }

#pragma unroll
    for (int nt = 0; nt < NTW; ++nt)
#pragma unroll
        for (int r = 0; r < 4; ++r) {
            const size_t off = (size_t)(r0 + 4 * g + r) * COUT + (w * NTW + nt) * 16 + q16;
            if constexpr (BF16OUT) ((u16*)Hout)[off] = f2bf(acc[nt][r]);
            else                   ((float*)Hout)[off] = acc[nt][r];
        }
}

// ---------------------------------------------------------------------------
// Pool stage 1: partial sums.  Grid 256 blocks = 8 b x 32 chunks of 32 rows.
// partial[b][ch][64] = sum over the chunk's 32 rows.
// ---------------------------------------------------------------------------
__global__ __launch_bounds__(256)
void pool_partial(const float* __restrict__ H2, float* __restrict__ partial) {
    const int b  = blockIdx.x >> 5;
    const int ch = blockIdx.x & 31;
    const int tid = threadIdx.x;
    const int o = tid & 63;
    const int g = tid >> 6;

    __shared__ float red[4][64];
    float acc = 0.f;
#pragma unroll
    for (int i = 0; i < 8; ++i) {
        const int n = ch * 32 + g * 8 + i;
        acc += H2[((size_t)b * NN + n) * 64 + o];
    }
    red[g][o] = acc;
    __syncthreads();
    if (g == 0)
        partial[((size_t)b * 32 + ch) * 64 + o] =
            (red[0][o] + red[1][o]) + (red[2][o] + red[3][o]);
}

// ---------------------------------------------------------------------------
// Pool stage 2: final reduce + 3-layer MLP.  8 blocks (one per b); reads
// 32x64 partials (L2-hot) -> mean -> MLP.
// ---------------------------------------------------------------------------
__global__ __launch_bounds__(256)
void pool_mlp2(const float* __restrict__ partial,
               const float* __restrict__ W1, const float* __restrict__ b1,
               const float* __restrict__ W2, const float* __restrict__ b2,
               const float* __restrict__ W3, const float* __restrict__ b3,
               float* __restrict__ out) {
    const int b = blockIdx.x;
    const int tid = threadIdx.x;       // 256
    const int o = tid & 63;
    const int g = tid >> 6;
    __shared__ float red[4][64];
    __shared__ float mean[64];
    __shared__ float h1[32];
    __shared__ float h2[16];

    float acc = 0.f;
#pragma unroll
    for (int c = 0; c < 8; ++c)
        acc += partial[((size_t)b * 32 + g * 8 + c) * 64 + o];
    red[g][o] = acc;
    __syncthreads();
    if (g == 0)
        mean[o] = ((red[0][o] + red[1][o]) + (red[2][o] + red[3][o])) * (1.0f / 1024.0f);
    __syncthreads();

    if (tid < 32) {
        float a = b1[tid];
#pragma unroll
        for (int f = 0; f < 64; ++f) a = fmaf(mean[f], W1[f * 32 + tid], a);
        h1[tid] = fmaxf(a, 0.f);
    }
    __syncthreads();
    if (tid < 16) {
        float a = b2[tid];
#pragma unroll
        for (int f = 0; f < 32; ++f) a = fmaf(h1[f], W2[f * 16 + tid], a);
        h2[tid] = fmaxf(a, 0.f);
    }
    __syncthreads();
    if (tid == 0) {
        float a = b3[0];
#pragma unroll
        for (int f = 0; f < 16; ++f) a = fmaf(h2[f], W3[f], a);
        out[b] = a;
    }
}

// ---------------------------------------------------------------------------
extern "C" void kernel_launch(void* const* d_in, const int* in_sizes, int n_in,
                              void* d_out, int out_size, void* d_ws, size_t ws_size,
                              hipStream_t stream) {
    const float* X   = (const float*)d_in[0];
    const float* A   = (const float*)d_in[1];
    const float* Wq1 = (const float*)d_in[2];
    const float* Wk1 = (const float*)d_in[3];
    const float* Wv1 = (const float*)d_in[4];
    const float* Wo1 = (const float*)d_in[5];
    const float* Wq2 = (const float*)d_in[6];
    const float* Wk2 = (const float*)d_in[7];
    const float* Wv2 = (const float*)d_in[8];
    const float* Wo2 = (const float*)d_in[9];
    const float* W1  = (const float*)d_in[10];
    const float* b1  = (const float*)d_in[11];
    const float* W2  = (const float*)d_in[12];
    const float* b2  = (const float*)d_in[13];
    const float* W3  = (const float*)d_in[14];
    const float* b3  = (const float*)d_in[15];
    float* out = (float*)d_out;

    // workspace layout (u16 units unless noted)
    u32* bits   = (u32*)d_ws;                      // 1 MB
    u16* base   = (u16*)(bits + 262144);
    u16* Qb1    = base;  base += 8388608;
    u16* Kb1    = base;  base += 8388608;
    u16* VT1    = base;  base += 8388608;          // chunk-major V
    u16* ctx1b  = base;  base += 8388608;          // bf16 ctx [B,N,1024]
    u16* WoT1   = base;  base += 131072;           // [128][1024]
    u16* Qb2    = base;  base += 4194304;
    u16* Kb2    = base;  base += 4194304;
    u16* VT2    = base;  base += 4194304;
    u16* ctx2b  = base;  base += 4194304;          // bf16 ctx [B,N,512]
    u16* WoT2   = base;  base += 32768;            // [64][512]
    u16* Xb     = base;  base += 524288;           // bf16 X [8192][64]
    u16* WqkvT1 = base;  base += 196608;           // [3072][64]
    u16* WqkvT2 = base;  base += 196608;           // [1536][128]
    u16* H1b    = base;  base += 1048576;          // bf16 H1 [8192][128]
    float* H2   = (float*)base;                    // f32 [B,N,64] (1MB floats)
    float* partial = H2 + 524288;                  // f32 [8][32][64]

    const int ROWS = NB * NN;                     // 8192
    const float LOG2E = 1.4426950408889634f;

    // prep (independent)
    mask_bits<<<ROWS, 256, 0, stream>>>(A, bits);
    cvt_bf16<<<ROWS * 64 / 8 / 256, 256, 0, stream>>>(X, Xb);
    cvt_qkvT<64, 1024><<<3072 * 64 / 8 / 256, 256, 0, stream>>>(Wq1, Wk1, Wv1, WqkvT1);
    cvt_qkvT<128, 512><<<1536 * 128 / 8 / 256, 256, 0, stream>>>(Wq2, Wk2, Wv2, WqkvT2);
    cvt_woT<1024, 128><<<128 * 1024 / 8 / 256, 256, 0, stream>>>(Wo1, WoT1);
    cvt_woT<512, 64><<<64 * 512 / 8 / 256, 256, 0, stream>>>(Wo2, WoT2);

    // ----- layer 1 (D = 128) -----
    proj_mfma<64, 1024, 128><<<ROWS / 16, 256, 0, stream>>>(
        Xb, WqkvT1, Qb1, Kb1, VT1, 0.08838834764831845f * LOG2E);
    attn_v10<128><<<512, 256, 0, stream>>>(Qb1, Kb1, VT1, bits, ctx1b);
    wo_mfma<1024, 128, true><<<ROWS / 16, 256, 0, stream>>>(ctx1b, WoT1, H1b);

    // ----- layer 2 (D = 64) -----
    proj_mfma<128, 512, 64><<<ROWS / 16, 256, 0, stream>>>(
        H1b, WqkvT2, Qb2, Kb2, VT2, 0.125f * LOG2E);
    attn_v10<64><<<512, 256, 0, stream>>>(Qb2, Kb2, VT2, bits, ctx2b);
    wo_mfma<512, 64, false><<<ROWS / 16, 256, 0, stream>>>(ctx2b, WoT2, H2);

    // ----- pool + MLP (2-stage: parallel reduce, tiny MLP) -----
    pool_partial<<<256, 256, 0, stream>>>(H2, partial);
    pool_mlp2<<<NB, 256, 0, stream>>>(partial, W1, b1, W2, b2, W3, b3, out);
}

// Round 16
// 212.813 us; speedup vs baseline: 3.5407x; 1.0280x over previous
//
#include <hip/hip_runtime.h>
#include <hip/hip_bf16.h>
#include <math.h>

// B=8, N=1024, F=64, HEADS=8, u1=128, u2=64
#define NB 8
#define NN 1024
#define NH 8

typedef __attribute__((ext_vector_type(8))) short bf16x8;
typedef __attribute__((ext_vector_type(4))) float f32x4;
typedef unsigned int u32;
typedef unsigned short u16;

__device__ __forceinline__ u16 f2bf(float f) {
    union { float f; u32 u; } v; v.f = f;
    const u32 u = v.u;
    return (u16)((u + 0x7fffu + ((u >> 16) & 1u)) >> 16);
}

// packed f32x2 -> bf16x2 (RTNE), dst.lo = lo, dst.hi = hi
__device__ __forceinline__ u32 cvt_pk_bf16(float lo, float hi) {
    u32 r;
    asm("v_cvt_pk_bf16_f32 %0, %1, %2" : "=v"(r) : "v"(lo), "v"(hi));
    return r;
}

// ---------------------------------------------------------------------------
// Mask bit-pack: A [B,N,N] f32 (0/1) -> bits [B*N, 32] u32 (bit=1 => masked)
// ---------------------------------------------------------------------------
__global__ __launch_bounds__(256) void mask_bits(const float* __restrict__ A,
                                                 u32* __restrict__ bits) {
    const int row = blockIdx.x;            // 0..B*N-1
    const int tid = threadIdx.x;
    const int lane = tid & 63;
    const float* __restrict__ ar = A + (size_t)row * NN;
#pragma unroll
    for (int it = 0; it < 4; ++it) {
        const int i = it * 256 + tid;
        const unsigned long long bal = __ballot(ar[i] != 0.0f);
        const int w0 = (it * 256 + (tid & ~63)) >> 5;
        if (lane == 0)  bits[(size_t)row * 32 + w0]     = (u32)bal;
        if (lane == 32) bits[(size_t)row * 32 + w0 + 1] = (u32)(bal >> 32);
    }
}

// ---------------------------------------------------------------------------
// f32 -> bf16 vector convert (8 elems/thread).
// ---------------------------------------------------------------------------
__global__ __launch_bounds__(256)
void cvt_bf16(const float* __restrict__ in, u16* __restrict__ out) {
    const int i = blockIdx.x * 256 + threadIdx.x;
    const float4 a = ((const float4*)in)[2 * i];
    const float4 b = ((const float4*)in)[2 * i + 1];
    u16 t[8] = {f2bf(a.x), f2bf(a.y), f2bf(a.z), f2bf(a.w),
                f2bf(b.x), f2bf(b.y), f2bf(b.z), f2bf(b.w)};
    ((uint4*)out)[i] = *(uint4*)t;
}

// ---------------------------------------------------------------------------
// QKV weight transpose+bf16: WT[c][f] over c in [0,3*HD) = {Wq|Wk|Wv}[f][c%HD]
// ---------------------------------------------------------------------------
template <int KIN, int HD>
__global__ __launch_bounds__(256)
void cvt_qkvT(const float* __restrict__ Wq, const float* __restrict__ Wk,
              const float* __restrict__ Wv, u16* __restrict__ WT) {
    const int idx = blockIdx.x * 256 + threadIdx.x;   // c*(KIN/8) + f8
    const int c  = idx / (KIN / 8);
    const int f0 = (idx % (KIN / 8)) * 8;
    const float* __restrict__ W = (c < HD) ? Wq : (c < 2 * HD) ? Wk : Wv;
    const int cc = c % HD;
    u16 tmp[8];
#pragma unroll
    for (int j = 0; j < 8; ++j)
        tmp[j] = f2bf(W[(size_t)(f0 + j) * HD + cc]);
    *(uint4*)&WT[(size_t)c * KIN + f0] = *(uint4*)tmp;
}

// ---------------------------------------------------------------------------
// Wo transpose+bf16: WoT[n][k] = bf16(Wo[k][n]).
// ---------------------------------------------------------------------------
template <int CIN, int COUT>
__global__ __launch_bounds__(256)
void cvt_woT(const float* __restrict__ Wo, u16* __restrict__ WoT) {
    const int idx = blockIdx.x * 256 + threadIdx.x;   // n*CIN/8 + k8
    const int n  = idx / (CIN / 8);
    const int k0 = (idx % (CIN / 8)) * 8;
    u16 tmp[8];
#pragma unroll
    for (int j = 0; j < 8; ++j)
        tmp[j] = f2bf(Wo[(size_t)(k0 + j) * COUT + n]);
    *(uint4*)&WoT[(size_t)n * CIN + k0] = *(uint4*)tmp;
}

// ---------------------------------------------------------------------------
// MFMA QKV projection (R12-verified).  Xb: [rows][KIN] bf16.  WT: [3*HD][KIN].
// Outputs: Qb [bh][n][D] (x qscale), Kb same, VT chunk-major permuted
// [bh][ch][D][32''] with n'' = 8g + r + 4*grp for this 16-row tile.
// ---------------------------------------------------------------------------
template <int KIN, int HD, int D>
__global__ __launch_bounds__(256)
void proj_mfma(const u16* __restrict__ Xb,
               const u16* __restrict__ WT,
               u16* __restrict__ Qb,
               u16* __restrict__ Kb,
               u16* __restrict__ VT,
               const float qscale) {
    constexpr int NKT = KIN / 32;          // k-steps (2 / 4)
    constexpr int NTW = (3 * HD / 16) / 4; // n-tiles per wave (48 / 24)

    const int tid  = threadIdx.x;
    const int w    = tid >> 6;
    const int lane = tid & 63;
    const int g    = lane >> 4;
    const int q16  = lane & 15;
    const int r0   = blockIdx.x * 16;
    const int b    = r0 >> 10;
    const int n0   = r0 & 1023;
    const int ch   = n0 >> 5;
    const int grp  = (n0 >> 4) & 1;

    bf16x8 af[NKT];
#pragma unroll
    for (int t = 0; t < NKT; ++t)
        af[t] = *(const bf16x8*)&Xb[(size_t)(r0 + q16) * KIN + t * 32 + g * 8];

#pragma unroll 1
    for (int i = 0; i < NTW; ++i) {
        const int nt = w + 4 * i;
        const int c0 = nt * 16;
        f32x4 acc = (f32x4)0.f;
#pragma unroll
        for (int t = 0; t < NKT; ++t) {
            const bf16x8 wf = *(const bf16x8*)&WT[(size_t)(c0 + q16) * KIN + t * 32 + g * 8];
            acc = __builtin_amdgcn_mfma_f32_16x16x32_bf16(af[t], wf, acc, 0, 0, 0);
        }

        const int wcl = c0 / HD;           // 0=Q 1=K 2=V (wave-uniform)
        const int cc  = c0 % HD;
        const int h   = cc / D;
        const int d0  = cc % D;
        const int bh  = b * NH + h;

        if (wcl == 2) {
            u16 tmp[4];
#pragma unroll
            for (int r = 0; r < 4; ++r) tmp[r] = f2bf(acc[r]);
            *(uint2*)&VT[(((size_t)bh * 32 + ch) * D + d0 + q16) * 32
                         + 8 * g + 4 * grp] = *(uint2*)tmp;
        } else {
            u16* __restrict__ O = wcl ? Kb : Qb;
            const float sc = wcl ? 1.0f : qscale;
#pragma unroll
            for (int r = 0; r < 4; ++r)
                O[((size_t)bh * NN + n0 + 4 * g + r) * D + d0 + q16] = f2bf(acc[r] * sc);
        }
    }
}

// ---------------------------------------------------------------------------
// MFMA flash attention v11: v10's verified body math with
//   - KVBLK=64 (16 chunks): half the barriers, 68 MFMA per barrier
//   - V LDS stride 144B + (vD,vHalf)->vD*144+vHalf*64 write map: per-cycle
//     conflict-free reads AND writes (80B stride aliased q16<->q16+8)
//   - l via ones-MFMA: accL = mfma(pa, ones) -> no VALU l-adds, and accL
//     is already in C-layout row order -> shuffle-free epilogue
//   - s_setprio(1) around MFMA clusters (T5)
// Grid 512 blocks = 8 XCDs x 8 bh x 8 q-blocks; block = 4 waves x 32q.
// ---------------------------------------------------------------------------
template <int D>
__global__ __launch_bounds__(256, 2)
void attn_v11(const u16* __restrict__ Qb,
              const u16* __restrict__ Kb,
              const u16* __restrict__ VT,
              const u32* __restrict__ bits,
              u16* __restrict__ Ob) {
    constexpr int ND4 = D / 32;            // QK k-steps per 16-key subtile (4/2)
    constexpr int NDT = D / 16;            // PV d-tiles (8/4)
    constexpr int KROWB = 2 * D;           // K LDS row bytes (256/128)
    constexpr int KBYTES = 64 * KROWB;     // 16K / 8K
    constexpr int VROWB = 144;             // 64 keys * 2B + 16B pad
    constexpr int VBYTES = D * VROWB;      // 18K / 9K

    const int tid  = threadIdx.x;
    const int w    = tid >> 6;
    const int lane = tid & 63;
    const int g    = lane >> 4;            // 0..3
    const int q16  = lane & 15;

    // 512 blocks -> 8 XCDs x 8 bh x 8 q-blocks (bijective; bid%8 = XCD)
    const int xcd    = blockIdx.x & 7;
    const int within = blockIdx.x >> 3;    // 0..63
    const int bh     = xcd * 8 + (within >> 3);
    const int b      = bh >> 3, h = bh & 7;
    const int q0     = ((within & 7) * 4 + w) * 32;   // 32 q-rows per wave

    const u16* __restrict__ qbase = Qb + (size_t)bh * NN * D;
    const u16* __restrict__ kbase = Kb + (size_t)bh * NN * D;
    const u16* __restrict__ vbase = VT + (size_t)bh * 32 * D * 32;  // 32-key-group major
    const u32* __restrict__ brow0 = bits + ((size_t)b * NN + q0 + q16) * 32;
    const u32* __restrict__ brow1 = brow0 + 16 * 32;

    __shared__ alignas(16) char KsB[2][KBYTES];
    __shared__ alignas(16) char VsB[2][VBYTES];

    // staging mapping (64B per thread each for K and V)
    bool doK, doV;
    int kRow = 0, kU0 = 0, vD = 0, vHalf = 0;
    if constexpr (D == 128) {
        doK = true; doV = true;
        kRow = tid >> 2;           kU0 = (tid & 3) * 4;    // 64 rows x 16 units
        vD   = tid >> 1;           vHalf = tid & 1;        // 128 rows x 2 halves
    } else {
        doK = (tid < 128); doV = !doK;
        kRow = (tid & 127) >> 1;   kU0 = (tid & 1) * 4;    // 64 rows x 8 units
        vD   = (tid & 127) >> 1;   vHalf = tid & 1;        // 64 rows x 2 halves
    }

    // Q as B-fragment: col=q16=q, k = f*32 + g*8 + j; 2 q-subtiles
    bf16x8 qf[2][ND4];
#pragma unroll
    for (int qs = 0; qs < 2; ++qs)
#pragma unroll
        for (int f = 0; f < ND4; ++f)
            qf[qs][f] = *(const bf16x8*)
                &qbase[(size_t)(q0 + qs * 16 + q16) * D + f * 32 + g * 8];

    f32x4 acc[2][NDT];
    f32x4 accL[2];
#pragma unroll
    for (int qs = 0; qs < 2; ++qs) {
        accL[qs] = (f32x4)0.f;
#pragma unroll
        for (int dt = 0; dt < NDT; ++dt) acc[qs][dt] = (f32x4)0.f;
    }

    const short oneb = (short)0x3F80;      // bf16 1.0
    const bf16x8 ones = {oneb, oneb, oneb, oneb, oneb, oneb, oneb, oneb};

    uint4 skr0, skr1, skr2, skr3, svr0, svr1, svr2, svr3;
    auto stage_load = [&](int ch) {
        if (doK) {
            const u16* src = kbase + (size_t)(ch * 64 + kRow) * D + kU0 * 8;
            skr0 = *(const uint4*)(src);
            skr1 = *(const uint4*)(src + 8);
            skr2 = *(const uint4*)(src + 16);
            skr3 = *(const uint4*)(src + 24);
        }
        if (doV) {
            const u16* src = vbase + ((size_t)(ch * 2 + vHalf) * D + vD) * 32;
            svr0 = *(const uint4*)(src);
            svr1 = *(const uint4*)(src + 8);
            svr2 = *(const uint4*)(src + 16);
            svr3 = *(const uint4*)(src + 24);
        }
    };
    auto stage_write = [&](int buf) {
        if (doK) {
            char* kr = KsB[buf] + kRow * KROWB;
            *(uint4*)(kr + (((kU0 + 0) ^ (kRow & 7)) * 16)) = skr0;
            *(uint4*)(kr + (((kU0 + 1) ^ (kRow & 7)) * 16)) = skr1;
            *(uint4*)(kr + (((kU0 + 2) ^ (kRow & 7)) * 16)) = skr2;
            *(uint4*)(kr + (((kU0 + 3) ^ (kRow & 7)) * 16)) = skr3;
        }
        if (doV) {
            char* vr = VsB[buf] + vD * VROWB + vHalf * 64;
            *(uint4*)(vr)      = svr0;
            *(uint4*)(vr + 16) = svr1;
            *(uint4*)(vr + 32) = svr2;
            *(uint4*)(vr + 48) = svr3;
        }
    };

    // prologue: buf0 = chunk 0; chunk 1 in regs
    stage_load(0);
    stage_write(0);
    stage_load(1);
    __syncthreads();

#pragma unroll 1
    for (int ch = 0; ch < 16; ++ch) {
        const int cur = ch & 1;
        if (ch + 1 < 16) stage_write(cur ^ 1);
        if (ch + 2 < 16) stage_load(ch + 2);

        const uint2 bwA = *(const uint2*)(brow0 + ch * 2);
        const uint2 bwB = *(const uint2*)(brow1 + ch * 2);

        // QK^T over 4 16-key subtiles (kf loaded per-subtile to cap liveness)
        f32x4 s[2][4];
#pragma unroll
        for (int qs = 0; qs < 2; ++qs)
#pragma unroll
            for (int kb = 0; kb < 4; ++kb) s[qs][kb] = (f32x4)0.f;

        __builtin_amdgcn_s_setprio(1);
#pragma unroll
        for (int kb = 0; kb < 4; ++kb) {
            bf16x8 kf[ND4];
#pragma unroll
            for (int f = 0; f < ND4; ++f)
                kf[f] = *(const bf16x8*)
                    (KsB[cur] + (kb * 16 + q16) * KROWB + (((f * 4 + g) ^ (q16 & 7)) * 16));
#pragma unroll
            for (int f = 0; f < ND4; ++f) {
                s[0][kb] = __builtin_amdgcn_mfma_f32_16x16x32_bf16(kf[f], qf[0][f], s[0][kb], 0, 0, 0);
                s[1][kb] = __builtin_amdgcn_mfma_f32_16x16x32_bf16(kf[f], qf[1][f], s[1][kb], 0, 0, 0);
            }
        }
        __builtin_amdgcn_s_setprio(0);

        // V B-fragments (issue LDS reads before softmax for overlap)
        bf16x8 vf[2][NDT];
#pragma unroll
        for (int kg = 0; kg < 2; ++kg)
#pragma unroll
            for (int dt = 0; dt < NDT; ++dt)
                vf[kg][dt] = *(const bf16x8*)
                    (VsB[cur] + (dt * 16 + q16) * VROWB + kg * 64 + g * 16);

        // softmax (no max tracking): reg r of s[qs][kb] = key kb*16+4g+r
        union { u32 u[4]; bf16x8 v; } pa[2][2];
#pragma unroll
        for (int qs = 0; qs < 2; ++qs) {
            const u32 w0 = qs ? bwB.x : bwA.x;
            const u32 w1 = qs ? bwB.y : bwA.y;
#pragma unroll
            for (int kb = 0; kb < 4; ++kb) {
                const u32 sh = ((kb >> 1) ? w1 : w0) >> (g * 4 + (kb & 1) * 16);
                float p[4];
#pragma unroll
                for (int r = 0; r < 4; ++r) {
                    const float e = exp2f(s[qs][kb][r]);
                    p[r] = ((sh >> r) & 1u) ? 0.f : e;
                }
                pa[qs][kb >> 1].u[(kb & 1) * 2 + 0] = cvt_pk_bf16(p[0], p[1]);
                pa[qs][kb >> 1].u[(kb & 1) * 2 + 1] = cvt_pk_bf16(p[2], p[3]);
            }
        }

        // PV + l-via-ones MFMA
        __builtin_amdgcn_s_setprio(1);
#pragma unroll
        for (int kg = 0; kg < 2; ++kg) {
            accL[0] = __builtin_amdgcn_mfma_f32_16x16x32_bf16(pa[0][kg].v, ones, accL[0], 0, 0, 0);
            accL[1] = __builtin_amdgcn_mfma_f32_16x16x32_bf16(pa[1][kg].v, ones, accL[1], 0, 0, 0);
#pragma unroll
            for (int dt = 0; dt < NDT; ++dt) {
                acc[0][dt] = __builtin_amdgcn_mfma_f32_16x16x32_bf16(pa[0][kg].v, vf[kg][dt], acc[0][dt], 0, 0, 0);
                acc[1][dt] = __builtin_amdgcn_mfma_f32_16x16x32_bf16(pa[1][kg].v, vf[kg][dt], acc[1][dt], 0, 0, 0);
            }
        }
        __builtin_amdgcn_s_setprio(0);

        __syncthreads();
    }

    // epilogue: accL[qs][r] = l for q-row g*4+r (C-layout) -> no shuffles
#pragma unroll
    for (int qs = 0; qs < 2; ++qs) {
        float ivr[4];
#pragma unroll
        for (int r = 0; r < 4; ++r) ivr[r] = 1.0f / accL[qs][r];
#pragma unroll
        for (int dt = 0; dt < NDT; ++dt)
#pragma unroll
            for (int r = 0; r < 4; ++r) {
                const int q = q0 + qs * 16 + g * 4 + r;
                Ob[(((size_t)b * NN + q) * NH + h) * D + dt * 16 + q16] =
                    f2bf(acc[qs][dt][r] * ivr[r]);
            }
    }
}

// ---------------------------------------------------------------------------
// Output projection via MFMA (R11/R12-verified).
// ---------------------------------------------------------------------------
template <int CIN, int COUT, bool BF16OUT>
__global__ __launch_bounds__(256)
void wo_mfma(const u16* __restrict__ ctxb,
             const u16* __restrict__ WoT,
             void* __restrict__ Hout) {
    constexpr int NTW = COUT / 64;         // n-tiles per wave (2 / 1)
    const int tid  = threadIdx.x;
    const int w    = tid >> 6;
    const int lane = tid & 63;
    const int g    = lane >> 4;
    const int q16  = lane & 15;
    const int r0   = blockIdx.x * 16;

    f32x4 acc[NTW];
#pragma unroll
    for (int nt = 0; nt < NTW; ++nt) acc[nt] = (f32x4)0.f;

    const u16* __restrict__ arow = ctxb + (size_t)(r0 + q16) * CIN + g * 8;

#pragma unroll 4
    for (int k0 = 0; k0 < CIN; k0 += 32) {
        const bf16x8 af = *(const bf16x8*)(arow + k0);
#pragma unroll
        for (int nt = 0; nt < NTW; ++nt) {
            const int n = (w * NTW + nt) * 16 + q16;
            const bf16x8 wf = *(const bf16x8*)&WoT[(size_t)n * CIN + k0 + g * 8];
            acc[nt] = __builtin_amdgcn_mfma_f32_16x16x32_bf16(af, wf, acc[nt], 0, 0, 0);
        }
    }

#pragma unroll
    for (int nt = 0; nt < NTW; ++nt)
#pragma unroll
        for (int r = 0; r < 4; ++r) {
            const size_t off = (size_t)(r0 + 4 * g + r) * COUT + (w * NTW + nt) * 16 + q16;
            if constexpr (BF16OUT) ((u16*)Hout)[off] = f2bf(acc[nt][r]);
            else                   ((float*)Hout)[off] = acc[nt][r];
        }
}

// ---------------------------------------------------------------------------
// Pool stage 1: partial sums.  Grid 256 blocks = 8 b x 32 chunks of 32 rows.
// ---------------------------------------------------------------------------
__global__ __launch_bounds__(256)
void pool_partial(const float* __restrict__ H2, float* __restrict__ partial) {
    const int b  = blockIdx.x >> 5;
    const int ch = blockIdx.x & 31;
    const int tid = threadIdx.x;
    const int o = tid & 63;
    const int g = tid >> 6;

    __shared__ float red[4][64];
    float acc = 0.f;
#pragma unroll
    for (int i = 0; i < 8; ++i) {
        const int n = ch * 32 + g * 8 + i;
        acc += H2[((size_t)b * NN + n) * 64 + o];
    }
    red[g][o] = acc;
    __syncthreads();
    if (g == 0)
        partial[((size_t)b * 32 + ch) * 64 + o] =
            (red[0][o] + red[1][o]) + (red[2][o] + red[3][o]);
}

// ---------------------------------------------------------------------------
// Pool stage 2: final reduce + 3-layer MLP.  8 blocks (one per b).
// ---------------------------------------------------------------------------
__global__ __launch_bounds__(256)
void pool_mlp2(const float* __restrict__ partial,
               const float* __restrict__ W1, const float* __restrict__ b1,
               const float* __restrict__ W2, const float* __restrict__ b2,
               const float* __restrict__ W3, const float* __restrict__ b3,
               float* __restrict__ out) {
    const int b = blockIdx.x;
    const int tid = threadIdx.x;       // 256
    const int o = tid & 63;
    const int g = tid >> 6;
    __shared__ float red[4][64];
    __shared__ float mean[64];
    __shared__ float h1[32];
    __shared__ float h2[16];

    float acc = 0.f;
#pragma unroll
    for (int c = 0; c < 8; ++c)
        acc += partial[((size_t)b * 32 + g * 8 + c) * 64 + o];
    red[g][o] = acc;
    __syncthreads();
    if (g == 0)
        mean[o] = ((red[0][o] + red[1][o]) + (red[2][o] + red[3][o])) * (1.0f / 1024.0f);
    __syncthreads();

    if (tid < 32) {
        float a = b1[tid];
#pragma unroll
        for (int f = 0; f < 64; ++f) a = fmaf(mean[f], W1[f * 32 + tid], a);
        h1[tid] = fmaxf(a, 0.f);
    }
    __syncthreads();
    if (tid < 16) {
        float a = b2[tid];
#pragma unroll
        for (int f = 0; f < 32; ++f) a = fmaf(h1[f], W2[f * 16 + tid], a);
        h2[tid] = fmaxf(a, 0.f);
    }
    __syncthreads();
    if (tid == 0) {
        float a = b3[0];
#pragma unroll
        for (int f = 0; f < 16; ++f) a = fmaf(h2[f], W3[f], a);
        out[b] = a;
    }
}

// ---------------------------------------------------------------------------
extern "C" void kernel_launch(void* const* d_in, const int* in_sizes, int n_in,
                              void* d_out, int out_size, void* d_ws, size_t ws_size,
                              hipStream_t stream) {
    const float* X   = (const float*)d_in[0];
    const float* A   = (const float*)d_in[1];
    const float* Wq1 = (const float*)d_in[2];
    const float* Wk1 = (const float*)d_in[3];
    const float* Wv1 = (const float*)d_in[4];
    const float* Wo1 = (const float*)d_in[5];
    const float* Wq2 = (const float*)d_in[6];
    const float* Wk2 = (const float*)d_in[7];
    const float* Wv2 = (const float*)d_in[8];
    const float* Wo2 = (const float*)d_in[9];
    const float* W1  = (const float*)d_in[10];
    const float* b1  = (const float*)d_in[11];
    const float* W2  = (const float*)d_in[12];
    const float* b2  = (const float*)d_in[13];
    const float* W3  = (const float*)d_in[14];
    const float* b3  = (const float*)d_in[15];
    float* out = (float*)d_out;

    // workspace layout (u16 units unless noted)
    u32* bits   = (u32*)d_ws;                      // 1 MB
    u16* base   = (u16*)(bits + 262144);
    u16* Qb1    = base;  base += 8388608;
    u16* Kb1    = base;  base += 8388608;
    u16* VT1    = base;  base += 8388608;          // 32-key-group-major V
    u16* ctx1b  = base;  base += 8388608;          // bf16 ctx [B,N,1024]
    u16* WoT1   = base;  base += 131072;           // [128][1024]
    u16* Qb2    = base;  base += 4194304;
    u16* Kb2    = base;  base += 4194304;
    u16* VT2    = base;  base += 4194304;
    u16* ctx2b  = base;  base += 4194304;          // bf16 ctx [B,N,512]
    u16* WoT2   = base;  base += 32768;            // [64][512]
    u16* Xb     = base;  base += 524288;           // bf16 X [8192][64]
    u16* WqkvT1 = base;  base += 196608;           // [3072][64]
    u16* WqkvT2 = base;  base += 196608;           // [1536][128]
    u16* H1b    = base;  base += 1048576;          // bf16 H1 [8192][128]
    float* H2   = (float*)base;                    // f32 [B,N,64] (1MB floats)
    float* partial = H2 + 524288;                  // f32 [8][32][64]

    const int ROWS = NB * NN;                     // 8192
    const float LOG2E = 1.4426950408889634f;

    // prep (independent)
    mask_bits<<<ROWS, 256, 0, stream>>>(A, bits);
    cvt_bf16<<<ROWS * 64 / 8 / 256, 256, 0, stream>>>(X, Xb);
    cvt_qkvT<64, 1024><<<3072 * 64 / 8 / 256, 256, 0, stream>>>(Wq1, Wk1, Wv1, WqkvT1);
    cvt_qkvT<128, 512><<<1536 * 128 / 8 / 256, 256, 0, stream>>>(Wq2, Wk2, Wv2, WqkvT2);
    cvt_woT<1024, 128><<<128 * 1024 / 8 / 256, 256, 0, stream>>>(Wo1, WoT1);
    cvt_woT<512, 64><<<64 * 512 / 8 / 256, 256, 0, stream>>>(Wo2, WoT2);

    // ----- layer 1 (D = 128) -----
    proj_mfma<64, 1024, 128><<<ROWS / 16, 256, 0, stream>>>(
        Xb, WqkvT1, Qb1, Kb1, VT1, 0.08838834764831845f * LOG2E);
    attn_v11<128><<<512, 256, 0, stream>>>(Qb1, Kb1, VT1, bits, ctx1b);
    wo_mfma<1024, 128, true><<<ROWS / 16, 256, 0, stream>>>(ctx1b, WoT1, H1b);

    // ----- layer 2 (D = 64) -----
    proj_mfma<128, 512, 64><<<ROWS / 16, 256, 0, stream>>>(
        H1b, WqkvT2, Qb2, Kb2, VT2, 0.125f * LOG2E);
    attn_v11<64><<<512, 256, 0, stream>>>(Qb2, Kb2, VT2, bits, ctx2b);
    wo_mfma<512, 64, false><<<ROWS / 16, 256, 0, stream>>>(ctx2b, WoT2, H2);

    // ----- pool + MLP (2-stage: parallel reduce, tiny MLP) -----
    pool_partial<<<256, 256, 0, stream>>>(H2, partial);
    pool_mlp2<<<NB, 256, 0, stream>>>(partial, W1, b1, W2, b2, W3, b3, out);
}